// Round 1
// baseline (16937.219 us; speedup 1.0000x reference)
//
#include <hip/hip_runtime.h>

// ---------------------------------------------------------------------------
// Dims
// ---------------------------------------------------------------------------
// B=512 A=256 CIN=7 CC=16 D=48 H=8 DH=6 E=512 S=32 T=32 NL=4 STOT=64
// CONV_IN=4096 HID=8192 ENC=1536 DEC_HID=3072 DEC_OUT=1792
static const double SCALE_ = 6.928203230275509;  // sqrt(48)

__device__ inline float  fma_t(float a, float b, float c)  { return fmaf(a, b, c); }
__device__ inline double fma_t(double a, double b, double c){ return fma(a, b, c); }

// ---------------------------------------------------------------------------
// K1: BatchNorm partial sums (deterministic, fp64)
// x: [512, 256, 7]; per-channel sums over 131072 samples
// ---------------------------------------------------------------------------
__global__ __launch_bounds__(256) void bn_partial_kernel(const float* __restrict__ x,
                                                         double* __restrict__ part) {
  __shared__ double sh[256 * 14];
  const int tid = threadIdx.x;
  const int idx = blockIdx.x * 256 + tid;  // (b,a) pair, 0..131071
  const float* p = x + (size_t)idx * 7;
  for (int c = 0; c < 7; ++c) {
    double v = (double)p[c];
    sh[tid * 14 + c] = v;
    sh[tid * 14 + 7 + c] = v * v;
  }
  __syncthreads();
  if (tid < 14) {
    double acc = 0.0;
    for (int t = 0; t < 256; ++t) acc += sh[t * 14 + tid];
    part[blockIdx.x * 14 + tid] = acc;
  }
}

// K2: finalize BN stats -> per-channel scale/shift (fp64)
__global__ void bn_final_kernel(const double* __restrict__ part,
                                const float* __restrict__ g, const float* __restrict__ bb,
                                double* __restrict__ stat) {
  const int c = threadIdx.x;
  if (c < 7) {
    double s = 0.0, s2 = 0.0;
    for (int i = 0; i < 512; ++i) { s += part[i * 14 + c]; s2 += part[i * 14 + 7 + c]; }
    const double mean = s / 131072.0;
    const double var = s2 / 131072.0 - mean * mean;
    const double rstd = 1.0 / sqrt(var + 1e-5);
    const double scale = rstd * (double)g[c];
    stat[c] = scale;                          // x*scale + shift
    stat[7 + c] = (double)bb[c] - mean * scale;
  }
}

// ---------------------------------------------------------------------------
// K3: BN-apply + Conv1d(7->16,k=5,pad=2) + flatten -> xf [512, 16*256] fp64
// ---------------------------------------------------------------------------
__global__ __launch_bounds__(256) void conv_kernel(const float* __restrict__ x,
                                                   const float* __restrict__ wconv,
                                                   const float* __restrict__ cb,
                                                   const double* __restrict__ stat,
                                                   double* __restrict__ xf) {
  __shared__ double wsh[560 + 14];
  const int tid = threadIdx.x;
  for (int i = tid; i < 560; i += 256) wsh[i] = (double)wconv[i];
  for (int i = tid; i < 14; i += 256) wsh[560 + i] = stat[i];
  __syncthreads();
  const int idx = blockIdx.x * 256 + tid;    // b*4096 + o*256 + a
  const int a = idx & 255;
  const int o = (idx >> 8) & 15;
  const int b = idx >> 12;
  double acc = (double)cb[o];
  const float* xb = x + (size_t)b * (256 * 7);
  for (int k = 0; k < 5; ++k) {
    const int pos = a + k - 2;
    if (pos < 0 || pos >= 256) continue;
    const float* xp = xb + pos * 7;
    for (int ci = 0; ci < 7; ++ci) {
      const double xn = (double)xp[ci] * wsh[560 + ci] + wsh[567 + ci];
      acc = fma(xn, wsh[(o * 7 + ci) * 5 + k], acc);
    }
  }
  xf[idx] = acc;
}

// ---------------------------------------------------------------------------
// Tiled GEMM: C[M,N] = act(A[M,K] @ Bf[K,N] (+bias)); A,C of type T; B fp32.
// BM=BN=64, BK=16, 256 threads, 4x4 microtile. grid.z = split-K chunks.
// All shapes here divide the tile sizes exactly (no bounds checks).
// ---------------------------------------------------------------------------
template <typename T, bool BIAS, bool RELU>
__global__ __launch_bounds__(256) void gemm_kernel(const T* __restrict__ A,
                                                   const float* __restrict__ Bm,
                                                   const float* __restrict__ bias,
                                                   T* __restrict__ C,
                                                   const int M, const int N, const int K,
                                                   const int kc) {
  __shared__ T As[16][65];
  __shared__ T Bs[16][65];
  const int tid = threadIdx.x;
  const int tx = tid & 15, ty = tid >> 4;
  const int n0 = blockIdx.x * 64, m0 = blockIdx.y * 64;
  const int k0 = blockIdx.z * kc, kend = k0 + kc;
  const int ar = tid >> 2, ac = (tid & 3) * 4;
  const int br = tid >> 4, bc = (tid & 15) * 4;
  const T* Ap = A + (size_t)(m0 + ar) * K;
  const float* Bp = Bm + (size_t)br * N + n0 + bc;
  T acc[4][4] = {};
  for (int k = k0; k < kend; k += 16) {
    const T a0 = Ap[k + ac], a1 = Ap[k + ac + 1], a2 = Ap[k + ac + 2], a3 = Ap[k + ac + 3];
    const float4 bw = *(const float4*)(Bp + (size_t)k * N);
    As[ac][ar] = a0; As[ac + 1][ar] = a1; As[ac + 2][ar] = a2; As[ac + 3][ar] = a3;
    Bs[br][bc] = (T)bw.x; Bs[br][bc + 1] = (T)bw.y; Bs[br][bc + 2] = (T)bw.z; Bs[br][bc + 3] = (T)bw.w;
    __syncthreads();
#pragma unroll
    for (int kk = 0; kk < 16; ++kk) {
      T av[4], bv2[4];
#pragma unroll
      for (int i = 0; i < 4; ++i) av[i] = As[kk][ty * 4 + i];
#pragma unroll
      for (int j = 0; j < 4; ++j) bv2[j] = Bs[kk][tx * 4 + j];
#pragma unroll
      for (int i = 0; i < 4; ++i)
#pragma unroll
        for (int j = 0; j < 4; ++j) acc[i][j] = fma_t(av[i], bv2[j], acc[i][j]);
    }
    __syncthreads();
  }
  T* Cp = C + (size_t)blockIdx.z * M * N;
#pragma unroll
  for (int i = 0; i < 4; ++i) {
    const int row = m0 + ty * 4 + i;
#pragma unroll
    for (int j = 0; j < 4; ++j) {
      const int col = n0 + tx * 4 + j;
      T v = acc[i][j];
      if (BIAS) v += (T)bias[col];
      if (RELU) v = v > (T)0 ? v : (T)0;
      Cp[(size_t)row * N + col] = v;
    }
  }
}

// split-K=2 reduction + bias (fp64, deterministic)
__global__ __launch_bounds__(256) void reduce2_bias_kernel(const double* __restrict__ part,
                                                           const float* __restrict__ bias,
                                                           double* __restrict__ out,
                                                           const int MN, const int N) {
  const int i = blockIdx.x * 256 + threadIdx.x;
  if (i < MN) out[i] = part[i] + part[MN + i] + (double)bias[i % N];
}

// ---------------------------------------------------------------------------
// K5: prefill — one block per batch element. Full 4-layer pass in LDS (fp64),
// fills KV caches at positions [0,32). Layer 3: k/v projections only.
// ---------------------------------------------------------------------------
__global__ __launch_bounds__(256) void prefill_kernel(
    const double* __restrict__ toks,
    const float* __restrict__ lnq_g, const float* __restrict__ lnq_b,
    const float* __restrict__ Wq, const float* __restrict__ bq,
    const float* __restrict__ lnk_g, const float* __restrict__ lnk_b,
    const float* __restrict__ Wk, const float* __restrict__ bk,
    const float* __restrict__ lnv_g, const float* __restrict__ lnv_b,
    const float* __restrict__ Wv, const float* __restrict__ bvv,
    const float* __restrict__ Wo, const float* __restrict__ bo,
    const float* __restrict__ mln_g, const float* __restrict__ mln_b,
    const float* __restrict__ W1, const float* __restrict__ b1,
    const float* __restrict__ W2, const float* __restrict__ b2,
    double* __restrict__ kcache, double* __restrict__ vcache) {
  const int b = blockIdx.x, tid = threadIdx.x;
  __shared__ double xcur[1536], abuf[1536], qbuf[1536], kvbuf[3072];
  __shared__ double mean[32], rstd[32];
  double* kb = kvbuf;
  double* vb = kvbuf + 1536;

  for (int i = tid; i < 1536; i += 256) xcur[i] = toks[(size_t)b * 1536 + i];
  __syncthreads();

  for (int l = 0; l < 4; ++l) {
    if (tid < 32) {
      double s = 0.0, s2 = 0.0;
      for (int i = 0; i < 48; ++i) { const double v = xcur[tid * 48 + i]; s += v; s2 += v * v; }
      const double m = s / 48.0;
      mean[tid] = m;
      rstd[tid] = 1.0 / sqrt(s2 / 48.0 - m * m + 1e-5);
    }
    __syncthreads();
    const bool last = (l == 3);

    if (!last) {  // q projection
      for (int i = tid; i < 1536; i += 256) {
        const int t = i / 48, d = i % 48;
        abuf[i] = (xcur[i] - mean[t]) * rstd[t] * (double)lnq_g[l * 48 + d] + (double)lnq_b[l * 48 + d];
      }
      __syncthreads();
      for (int i = tid; i < 1536; i += 256) {
        const int t = i / 48, j = i % 48;
        double acc = (double)bq[l * 48 + j];
        const double* arow = abuf + t * 48;
        const float* wp = Wq + l * 2304 + j;
        for (int kk = 0; kk < 48; ++kk) acc = fma(arow[kk], (double)wp[kk * 48], acc);
        qbuf[i] = acc;
      }
      __syncthreads();
    }
    // k projection
    for (int i = tid; i < 1536; i += 256) {
      const int t = i / 48, d = i % 48;
      abuf[i] = (xcur[i] - mean[t]) * rstd[t] * (double)lnk_g[l * 48 + d] + (double)lnk_b[l * 48 + d];
    }
    __syncthreads();
    for (int i = tid; i < 1536; i += 256) {
      const int t = i / 48, j = i % 48;
      double acc = (double)bk[l * 48 + j];
      const double* arow = abuf + t * 48;
      const float* wp = Wk + l * 2304 + j;
      for (int kk = 0; kk < 48; ++kk) acc = fma(arow[kk], (double)wp[kk * 48], acc);
      kb[i] = acc;
    }
    __syncthreads();
    // v projection
    for (int i = tid; i < 1536; i += 256) {
      const int t = i / 48, d = i % 48;
      abuf[i] = (xcur[i] - mean[t]) * rstd[t] * (double)lnv_g[l * 48 + d] + (double)lnv_b[l * 48 + d];
    }
    __syncthreads();
    for (int i = tid; i < 1536; i += 256) {
      const int t = i / 48, j = i % 48;
      double acc = (double)bvv[l * 48 + j];
      const double* arow = abuf + t * 48;
      const float* wp = Wv + l * 2304 + j;
      for (int kk = 0; kk < 48; ++kk) acc = fma(arow[kk], (double)wp[kk * 48], acc);
      vb[i] = acc;
    }
    __syncthreads();
    // store k,v to cache at pos t
    for (int i = tid; i < 1536; i += 256) {
      const int t = i / 48, j = i % 48;
      const int h = j / 6, d = j % 6;
      const size_t ci = ((((size_t)b * 4 + l) * 8 + h) * 64 + t) * 6 + d;
      kcache[ci] = kb[i];
      vcache[ci] = vb[i];
    }

    if (!last) {
      // attention: thread = (token t, head h). mask only (t=0, j=31).
      const int t = tid >> 3, h = tid & 7;
      const double* qp = qbuf + t * 48 + h * 6;
      const double q0 = qp[0], q1 = qp[1], q2 = qp[2], q3 = qp[3], q4 = qp[4], q5 = qp[5];
      double mx = -1e300;
      for (int j = 0; j < 32; ++j) {
        const double* kp = kb + j * 48 + h * 6;
        double sv = q0 * kp[0];
        sv = fma(q1, kp[1], sv); sv = fma(q2, kp[2], sv); sv = fma(q3, kp[3], sv);
        sv = fma(q4, kp[4], sv); sv = fma(q5, kp[5], sv);
        sv /= SCALE_;
        if (t == 0 && j == 31) sv -= 999.0;
        mx = sv > mx ? sv : mx;
      }
      double den = 0, o0 = 0, o1 = 0, o2 = 0, o3 = 0, o4 = 0, o5 = 0;
      for (int j = 0; j < 32; ++j) {
        const double* kp = kb + j * 48 + h * 6;
        double sv = q0 * kp[0];
        sv = fma(q1, kp[1], sv); sv = fma(q2, kp[2], sv); sv = fma(q3, kp[3], sv);
        sv = fma(q4, kp[4], sv); sv = fma(q5, kp[5], sv);
        sv /= SCALE_;
        if (t == 0 && j == 31) sv -= 999.0;
        const double e = exp(sv - mx);
        den += e;
        const double* vp = vb + j * 48 + h * 6;
        o0 = fma(e, vp[0], o0); o1 = fma(e, vp[1], o1); o2 = fma(e, vp[2], o2);
        o3 = fma(e, vp[3], o3); o4 = fma(e, vp[4], o4); o5 = fma(e, vp[5], o5);
      }
      abuf[t * 48 + h * 6 + 0] = o0 / den;
      abuf[t * 48 + h * 6 + 1] = o1 / den;
      abuf[t * 48 + h * 6 + 2] = o2 / den;
      abuf[t * 48 + h * 6 + 3] = o3 / den;
      abuf[t * 48 + h * 6 + 4] = o4 / den;
      abuf[t * 48 + h * 6 + 5] = o5 / den;
      __syncthreads();
      // Wo + residual
      for (int i = tid; i < 1536; i += 256) {
        const int t2 = i / 48, j = i % 48;
        double acc = (double)bo[l * 48 + j];
        const double* orow = abuf + t2 * 48;
        const float* wp = Wo + l * 2304 + j;
        for (int kk = 0; kk < 48; ++kk) acc = fma(orow[kk], (double)wp[kk * 48], acc);
        xcur[i] = acc + xcur[i];
      }
      __syncthreads();
      // MLP LN
      if (tid < 32) {
        double s = 0.0, s2 = 0.0;
        for (int i = 0; i < 48; ++i) { const double v = xcur[tid * 48 + i]; s += v; s2 += v * v; }
        const double m = s / 48.0;
        mean[tid] = m;
        rstd[tid] = 1.0 / sqrt(s2 / 48.0 - m * m + 1e-5);
      }
      __syncthreads();
      for (int i = tid; i < 1536; i += 256) {
        const int t2 = i / 48, d = i % 48;
        qbuf[i] = (xcur[i] - mean[t2]) * rstd[t2] * (double)mln_g[l * 48 + d] + (double)mln_b[l * 48 + d];
      }
      __syncthreads();
      for (int i = tid; i < 3072; i += 256) {
        const int t2 = i / 96, jj = i % 96;
        double acc = (double)b1[l * 96 + jj];
        const double* arow = qbuf + t2 * 48;
        const float* wp = W1 + l * 4608 + jj;
        for (int kk = 0; kk < 48; ++kk) acc = fma(arow[kk], (double)wp[kk * 96], acc);
        kvbuf[i] = acc > 0 ? acc : 0;
      }
      __syncthreads();
      for (int i = tid; i < 1536; i += 256) {
        const int t2 = i / 48, j = i % 48;
        double acc = (double)b2[l * 48 + j];
        const double* hrow = kvbuf + t2 * 96;
        const float* wp = W2 + l * 4608 + j;
        for (int kk = 0; kk < 96; ++kk) acc = fma(hrow[kk], (double)wp[kk * 48], acc);
        abuf[i] = acc;  // no residual
      }
      __syncthreads();
      for (int i = tid; i < 1536; i += 256) xcur[i] = abuf[i];
      __syncthreads();
    }
  }
}

// ---------------------------------------------------------------------------
// K6: autoregressive loop — one wave (64 threads) per batch element.
// All 32 steps x 4 layers in-kernel (batch elements independent).
// ---------------------------------------------------------------------------
__global__ __launch_bounds__(64) void ar_kernel(
    const float* __restrict__ pos_enc, const float* __restrict__ u,
    const float* __restrict__ lnq_g, const float* __restrict__ lnq_b,
    const float* __restrict__ Wq, const float* __restrict__ bq,
    const float* __restrict__ lnk_g, const float* __restrict__ lnk_b,
    const float* __restrict__ Wk, const float* __restrict__ bk,
    const float* __restrict__ lnv_g, const float* __restrict__ lnv_b,
    const float* __restrict__ Wv, const float* __restrict__ bvv,
    const float* __restrict__ Wo, const float* __restrict__ bo,
    const float* __restrict__ mln_g, const float* __restrict__ mln_b,
    const float* __restrict__ W1, const float* __restrict__ b1,
    const float* __restrict__ W2, const float* __restrict__ b2,
    const float* __restrict__ emb,
    double* __restrict__ kcache, double* __restrict__ vcache,
    float* __restrict__ out_tok) {
  const int b = blockIdx.x, lane = threadIdx.x;
  __shared__ double xtk[48], anorm[144], qs[48], os[48], hh[96], probs[512];

  for (int step = 0; step < 32; ++step) {
    const int p = 32 + step;
    if (lane < 48) xtk[lane] = (double)pos_enc[step * 48 + lane];
    __syncthreads();

    for (int l = 0; l < 4; ++l) {
      // LN stats (shared across q,k,v)
      {
        const double v = lane < 48 ? xtk[lane] : 0.0;
        double s = v, s2 = v * v;
#pragma unroll
        for (int off = 32; off; off >>= 1) { s += __shfl_xor(s, off); s2 += __shfl_xor(s2, off); }
        const double m = s / 48.0;
        const double rs = 1.0 / sqrt(s2 / 48.0 - m * m + 1e-5);
        if (lane < 48) {
          const double xn = (xtk[lane] - m) * rs;
          anorm[lane]      = xn * (double)lnq_g[l * 48 + lane] + (double)lnq_b[l * 48 + lane];
          anorm[48 + lane] = xn * (double)lnk_g[l * 48 + lane] + (double)lnk_b[l * 48 + lane];
          anorm[96 + lane] = xn * (double)lnv_g[l * 48 + lane] + (double)lnv_b[l * 48 + lane];
        }
      }
      __syncthreads();
      // q,k,v projections (lane j computes dim j); write k,v to cache at pos p
      if (lane < 48) {
        const int j = lane;
        double aq = (double)bq[l * 48 + j], ak = (double)bk[l * 48 + j], av = (double)bvv[l * 48 + j];
        const float* wq = Wq + l * 2304 + j;
        const float* wk = Wk + l * 2304 + j;
        const float* wv = Wv + l * 2304 + j;
        for (int i = 0; i < 48; ++i) {
          aq = fma(anorm[i],      (double)wq[i * 48], aq);
          ak = fma(anorm[48 + i], (double)wk[i * 48], ak);
          av = fma(anorm[96 + i], (double)wv[i * 48], av);
        }
        qs[j] = aq;
        const int h = j / 6, d = j % 6;
        const size_t ci = ((((size_t)b * 4 + l) * 8 + h) * 64 + p) * 6 + d;
        kcache[ci] = ak;
        vcache[ci] = av;
      }
      __syncthreads();
      // attention over positions [0, p): 8 lanes per head
      {
        const int h = lane >> 3, r = lane & 7;
        const double q0 = qs[h * 6 + 0], q1 = qs[h * 6 + 1], q2 = qs[h * 6 + 2],
                     q3 = qs[h * 6 + 3], q4 = qs[h * 6 + 4], q5 = qs[h * 6 + 5];
        const double* kcb = kcache + ((((size_t)b * 4 + l) * 8 + h) * 64) * 6;
        const double* vcb = vcache + ((((size_t)b * 4 + l) * 8 + h) * 64) * 6;
        double sc[8];
        int nk = 0;
        double mx = -1e300;
        for (int j = r; j < p; j += 8) {
          const double* kp = kcb + j * 6;
          double sv = q0 * kp[0];
          sv = fma(q1, kp[1], sv); sv = fma(q2, kp[2], sv); sv = fma(q3, kp[3], sv);
          sv = fma(q4, kp[4], sv); sv = fma(q5, kp[5], sv);
          sv /= SCALE_;
          sc[nk++] = sv;
          mx = sv > mx ? sv : mx;
        }
#pragma unroll
        for (int off = 1; off < 8; off <<= 1) { const double o2 = __shfl_xor(mx, off); mx = o2 > mx ? o2 : mx; }
        double den = 0, o0 = 0, o1 = 0, o2a = 0, o3 = 0, o4 = 0, o5 = 0;
        int n = 0;
        for (int j = r; j < p; j += 8) {
          const double e = exp(sc[n++] - mx);
          den += e;
          const double* vp = vcb + j * 6;
          o0 = fma(e, vp[0], o0); o1 = fma(e, vp[1], o1); o2a = fma(e, vp[2], o2a);
          o3 = fma(e, vp[3], o3); o4 = fma(e, vp[4], o4); o5 = fma(e, vp[5], o5);
        }
#pragma unroll
        for (int off = 1; off < 8; off <<= 1) {
          den += __shfl_xor(den, off);
          o0 += __shfl_xor(o0, off); o1 += __shfl_xor(o1, off); o2a += __shfl_xor(o2a, off);
          o3 += __shfl_xor(o3, off); o4 += __shfl_xor(o4, off); o5 += __shfl_xor(o5, off);
        }
        if (r == 0) {
          os[h * 6 + 0] = o0 / den; os[h * 6 + 1] = o1 / den; os[h * 6 + 2] = o2a / den;
          os[h * 6 + 3] = o3 / den; os[h * 6 + 4] = o4 / den; os[h * 6 + 5] = o5 / den;
        }
      }
      __syncthreads();
      // Wo + residual
      double nx = 0;
      if (lane < 48) {
        double acc = (double)bo[l * 48 + lane];
        const float* wo = Wo + l * 2304 + lane;
        for (int i = 0; i < 48; ++i) acc = fma(os[i], (double)wo[i * 48], acc);
        nx = acc + xtk[lane];
      }
      __syncthreads();
      if (lane < 48) xtk[lane] = nx;
      __syncthreads();
      // MLP
      {
        const double v = lane < 48 ? xtk[lane] : 0.0;
        double s = v, s2 = v * v;
#pragma unroll
        for (int off = 32; off; off >>= 1) { s += __shfl_xor(s, off); s2 += __shfl_xor(s2, off); }
        const double m = s / 48.0;
        const double rs = 1.0 / sqrt(s2 / 48.0 - m * m + 1e-5);
        if (lane < 48)
          anorm[lane] = (xtk[lane] - m) * rs * (double)mln_g[l * 48 + lane] + (double)mln_b[l * 48 + lane];
      }
      __syncthreads();
      {
        double acc = (double)b1[l * 96 + lane];
        const float* w1 = W1 + l * 4608 + lane;
        for (int i = 0; i < 48; ++i) acc = fma(anorm[i], (double)w1[i * 96], acc);
        hh[lane] = acc > 0 ? acc : 0;
        if (lane < 32) {
          const int jj = 64 + lane;
          double a2 = (double)b1[l * 96 + jj];
          const float* w1b = W1 + l * 4608 + jj;
          for (int i = 0; i < 48; ++i) a2 = fma(anorm[i], (double)w1b[i * 96], a2);
          hh[jj] = a2 > 0 ? a2 : 0;
        }
      }
      __syncthreads();
      if (lane < 48) {
        double acc = (double)b2[l * 48 + lane];
        const float* w2 = W2 + l * 4608 + lane;
        for (int i = 0; i < 96; ++i) acc = fma(hh[i], (double)w2[i * 48], acc);
        nx = acc;
      }
      __syncthreads();
      if (lane < 48) xtk[lane] = nx;  // no residual
      __syncthreads();
    }

    // ---- sampling (fp64 softmax + scan) ----
    double lg[8];
#pragma unroll
    for (int t8 = 0; t8 < 8; ++t8) {
      const int e = t8 * 64 + lane;
      double acc = 0;
      for (int d0 = 0; d0 < 48; ++d0) acc = fma(xtk[d0], (double)emb[d0 * 512 + e], acc);
      lg[t8] = acc;
    }
    double mx = lg[0];
#pragma unroll
    for (int t8 = 1; t8 < 8; ++t8) mx = lg[t8] > mx ? lg[t8] : mx;
#pragma unroll
    for (int off = 32; off; off >>= 1) { const double o2 = __shfl_xor(mx, off); mx = o2 > mx ? o2 : mx; }
#pragma unroll
    for (int t8 = 0; t8 < 8; ++t8) probs[t8 * 64 + lane] = exp(lg[t8] - mx);
    __syncthreads();
    double loc[8], run = 0;
#pragma unroll
    for (int n2 = 0; n2 < 8; ++n2) { run += probs[lane * 8 + n2]; loc[n2] = run; }
    double incl = run;
    for (int off = 1; off < 64; off <<= 1) {
      const double t2 = __shfl_up(incl, off);
      if (lane >= off) incl += t2;
    }
    const double excl = incl - run;
    const double Ssum = __shfl(incl, 63);
    const double uu = (double)u[step * 512 + b];
    int cnt = 0;
#pragma unroll
    for (int n2 = 0; n2 < 8; ++n2) cnt += ((excl + loc[n2]) / Ssum < uu) ? 1 : 0;
#pragma unroll
    for (int off = 1; off < 64; off <<= 1) cnt += __shfl_xor(cnt, off);
    const int idx = cnt > 511 ? 511 : cnt;
    if (lane < 48) {
      const double sel = (double)emb[lane * 512 + idx];
      const double att = xtk[lane];
      out_tok[(size_t)b * 1536 + step * 48 + lane] = (float)((sel + att) - att);  // straight-through fwd
    }
    __syncthreads();
  }
}

// ---------------------------------------------------------------------------
// Launch
// ---------------------------------------------------------------------------
extern "C" void kernel_launch(void* const* d_in, const int* in_sizes, int n_in,
                              void* d_out, int out_size, void* d_ws, size_t ws_size,
                              hipStream_t stream) {
  const float* x      = (const float*)d_in[0];
  const float* u      = (const float*)d_in[1];
  const float* bn_g   = (const float*)d_in[2];
  const float* bn_b   = (const float*)d_in[3];
  const float* conv_w = (const float*)d_in[4];
  const float* conv_b = (const float*)d_in[5];
  const float* tk_W1  = (const float*)d_in[6];
  const float* tk_b1  = (const float*)d_in[7];
  const float* tk_W2  = (const float*)d_in[8];
  const float* tk_b2  = (const float*)d_in[9];
  const float* lnq_g  = (const float*)d_in[10];
  const float* lnq_b  = (const float*)d_in[11];
  const float* Wq     = (const float*)d_in[12];
  const float* bq     = (const float*)d_in[13];
  const float* lnk_g  = (const float*)d_in[14];
  const float* lnk_b  = (const float*)d_in[15];
  const float* Wk     = (const float*)d_in[16];
  const float* bk     = (const float*)d_in[17];
  const float* lnv_g  = (const float*)d_in[18];
  const float* lnv_b  = (const float*)d_in[19];
  const float* Wv     = (const float*)d_in[20];
  const float* bvv    = (const float*)d_in[21];
  const float* Wo     = (const float*)d_in[22];
  const float* bo     = (const float*)d_in[23];
  const float* mln_g  = (const float*)d_in[24];
  const float* mln_b  = (const float*)d_in[25];
  const float* W1     = (const float*)d_in[26];
  const float* b1     = (const float*)d_in[27];
  const float* W2     = (const float*)d_in[28];
  const float* b2     = (const float*)d_in[29];
  const float* emb    = (const float*)d_in[30];
  const float* pos    = (const float*)d_in[31];
  const float* dW1    = (const float*)d_in[32];
  const float* db1    = (const float*)d_in[33];
  const float* dW2    = (const float*)d_in[34];
  const float* db2    = (const float*)d_in[35];
  float* out = (float*)d_out;

  char* w = (char*)d_ws;
  size_t off = 0;
  auto alloc = [&](size_t bytes) {
    size_t o = off;
    off = (off + bytes + 255) & ~(size_t)255;
    return o;
  };
  const size_t o_bnp  = alloc(512 * 14 * 8);
  const size_t o_bns  = alloc(14 * 8);
  const size_t o_xf   = alloc(16777216);   // xf fp64; later reused for split-K partials (12.6MB)
  const size_t o_h    = alloc(33554432);   // h fp64; later reused for out_tok(3.1MB)+dh(6.3MB)
  const size_t o_toks = alloc(6291456);
  const size_t o_kc   = alloc(50331648);
  const size_t o_vc   = alloc(50331648);

  double* bnp  = (double*)(w + o_bnp);
  double* bns  = (double*)(w + o_bns);
  double* xf   = (double*)(w + o_xf);
  double* hbuf = (double*)(w + o_h);
  double* toks = (double*)(w + o_toks);
  double* kc   = (double*)(w + o_kc);
  double* vc   = (double*)(w + o_vc);
  double* part = (double*)(w + o_xf);                 // reuse (xf dead after G1)
  float*  otok = (float*)(w + o_h);                   // reuse (h dead after G2)
  float*  dh   = (float*)(w + o_h + 4194304);

  // 1-2: BatchNorm stats (deterministic fp64)
  bn_partial_kernel<<<512, 256, 0, stream>>>(x, bnp);
  bn_final_kernel<<<1, 64, 0, stream>>>(bnp, bn_g, bn_b, bns);
  // 3: BN-apply + conv + flatten -> xf [512,4096]
  conv_kernel<<<8192, 256, 0, stream>>>(x, conv_w, conv_b, bns, xf);
  // 4: h = relu(xf @ tk_W1 + b1)  [512,8192]
  gemm_kernel<double, true, true><<<dim3(128, 8, 1), 256, 0, stream>>>(
      xf, tk_W1, tk_b1, hbuf, 512, 8192, 4096, 4096);
  // 5: toks = h @ tk_W2 + b2 (split-K=2 into partials, then reduce)
  gemm_kernel<double, false, false><<<dim3(24, 8, 2), 256, 0, stream>>>(
      hbuf, tk_W2, nullptr, part, 512, 1536, 8192, 4096);
  reduce2_bias_kernel<<<3072, 256, 0, stream>>>(part, tk_b2, toks, 512 * 1536, 1536);
  // 6: prefill (fills KV caches, positions 0..31)
  prefill_kernel<<<512, 256, 0, stream>>>(toks,
      lnq_g, lnq_b, Wq, bq, lnk_g, lnk_b, Wk, bk, lnv_g, lnv_b, Wv, bvv,
      Wo, bo, mln_g, mln_b, W1, b1, W2, b2, kc, vc);
  // 7: autoregressive loop (32 steps x 4 layers, one wave per batch element)
  ar_kernel<<<512, 64, 0, stream>>>(pos, u,
      lnq_g, lnq_b, Wq, bq, lnk_g, lnk_b, Wk, bk, lnv_g, lnv_b, Wv, bvv,
      Wo, bo, mln_g, mln_b, W1, b1, W2, b2, emb, kc, vc, otok);
  // 8: decoder (fp32 — post-sampling, continuous path)
  gemm_kernel<float, true, true><<<dim3(48, 8, 1), 256, 0, stream>>>(
      otok, dW1, db1, dh, 512, 3072, 1536, 1536);
  gemm_kernel<float, true, false><<<dim3(28, 8, 1), 256, 0, stream>>>(
      dh, dW2, db2, out, 512, 1792, 3072, 3072);
}

// Round 2
// 13793.599 us; speedup vs baseline: 1.2279x; 1.2279x over previous
//
#include <hip/hip_runtime.h>

// ---------------------------------------------------------------------------
// Dims
// ---------------------------------------------------------------------------
// B=512 A=256 CIN=7 CC=16 D=48 H=8 DH=6 E=512 S=32 T=32 NL=4 STOT=64
// CONV_IN=4096 HID=8192 ENC=1536 DEC_HID=3072 DEC_OUT=1792
static const double SCALE_ = 6.928203230275509;  // sqrt(48)

__device__ inline float  fma_t(float a, float b, float c)  { return fmaf(a, b, c); }
__device__ inline double fma_t(double a, double b, double c){ return fma(a, b, c); }

// ---------------------------------------------------------------------------
// K1: BatchNorm partial sums (deterministic, fp64)
// ---------------------------------------------------------------------------
__global__ __launch_bounds__(256) void bn_partial_kernel(const float* __restrict__ x,
                                                         double* __restrict__ part) {
  __shared__ double sh[256 * 14];
  const int tid = threadIdx.x;
  const int idx = blockIdx.x * 256 + tid;  // (b,a) pair, 0..131071
  const float* p = x + (size_t)idx * 7;
  for (int c = 0; c < 7; ++c) {
    double v = (double)p[c];
    sh[tid * 14 + c] = v;
    sh[tid * 14 + 7 + c] = v * v;
  }
  __syncthreads();
  if (tid < 14) {
    double acc = 0.0;
    for (int t = 0; t < 256; ++t) acc += sh[t * 14 + tid];
    part[blockIdx.x * 14 + tid] = acc;
  }
}

// K2: finalize BN stats -> per-channel scale/shift (fp64)
__global__ void bn_final_kernel(const double* __restrict__ part,
                                const float* __restrict__ g, const float* __restrict__ bb,
                                double* __restrict__ stat) {
  const int c = threadIdx.x;
  if (c < 7) {
    double s = 0.0, s2 = 0.0;
    for (int i = 0; i < 512; ++i) { s += part[i * 14 + c]; s2 += part[i * 14 + 7 + c]; }
    const double mean = s / 131072.0;
    const double var = s2 / 131072.0 - mean * mean;
    const double rstd = 1.0 / sqrt(var + 1e-5);
    const double scale = rstd * (double)g[c];
    stat[c] = scale;                          // x*scale + shift
    stat[7 + c] = (double)bb[c] - mean * scale;
  }
}

// ---------------------------------------------------------------------------
// K3: BN-apply + Conv1d(7->16,k=5,pad=2) + flatten -> xf [512, 16*256] fp64
// ---------------------------------------------------------------------------
__global__ __launch_bounds__(256) void conv_kernel(const float* __restrict__ x,
                                                   const float* __restrict__ wconv,
                                                   const float* __restrict__ cb,
                                                   const double* __restrict__ stat,
                                                   double* __restrict__ xf) {
  __shared__ double wsh[560 + 14];
  const int tid = threadIdx.x;
  for (int i = tid; i < 560; i += 256) wsh[i] = (double)wconv[i];
  for (int i = tid; i < 14; i += 256) wsh[560 + i] = stat[i];
  __syncthreads();
  const int idx = blockIdx.x * 256 + tid;    // b*4096 + o*256 + a
  const int a = idx & 255;
  const int o = (idx >> 8) & 15;
  const int b = idx >> 12;
  double acc = (double)cb[o];
  const float* xb = x + (size_t)b * (256 * 7);
  for (int k = 0; k < 5; ++k) {
    const int pos = a + k - 2;
    if (pos < 0 || pos >= 256) continue;
    const float* xp = xb + pos * 7;
    for (int ci = 0; ci < 7; ++ci) {
      const double xn = (double)xp[ci] * wsh[560 + ci] + wsh[567 + ci];
      acc = fma(xn, wsh[(o * 7 + ci) * 5 + k], acc);
    }
  }
  xf[idx] = acc;
}

// ---------------------------------------------------------------------------
// Tiled GEMM: C[M,N] = act(A[M,K] @ Bf[K,N] (+bias)); A,C of type T; B fp32.
// BM=BN=64, BK=16, 256 threads, 4x4 microtile. grid.z = split-K chunks.
// ---------------------------------------------------------------------------
template <typename T, bool BIAS, bool RELU>
__global__ __launch_bounds__(256) void gemm_kernel(const T* __restrict__ A,
                                                   const float* __restrict__ Bm,
                                                   const float* __restrict__ bias,
                                                   T* __restrict__ C,
                                                   const int M, const int N, const int K,
                                                   const int kc) {
  __shared__ T As[16][65];
  __shared__ T Bs[16][65];
  const int tid = threadIdx.x;
  const int tx = tid & 15, ty = tid >> 4;
  const int n0 = blockIdx.x * 64, m0 = blockIdx.y * 64;
  const int k0 = blockIdx.z * kc, kend = k0 + kc;
  const int ar = tid >> 2, ac = (tid & 3) * 4;
  const int br = tid >> 4, bc = (tid & 15) * 4;
  const T* Ap = A + (size_t)(m0 + ar) * K;
  const float* Bp = Bm + (size_t)br * N + n0 + bc;
  T acc[4][4] = {};
  for (int k = k0; k < kend; k += 16) {
    const T a0 = Ap[k + ac], a1 = Ap[k + ac + 1], a2 = Ap[k + ac + 2], a3 = Ap[k + ac + 3];
    const float4 bw = *(const float4*)(Bp + (size_t)k * N);
    As[ac][ar] = a0; As[ac + 1][ar] = a1; As[ac + 2][ar] = a2; As[ac + 3][ar] = a3;
    Bs[br][bc] = (T)bw.x; Bs[br][bc + 1] = (T)bw.y; Bs[br][bc + 2] = (T)bw.z; Bs[br][bc + 3] = (T)bw.w;
    __syncthreads();
#pragma unroll
    for (int kk = 0; kk < 16; ++kk) {
      T av[4], bv2[4];
#pragma unroll
      for (int i = 0; i < 4; ++i) av[i] = As[kk][ty * 4 + i];
#pragma unroll
      for (int j = 0; j < 4; ++j) bv2[j] = Bs[kk][tx * 4 + j];
#pragma unroll
      for (int i = 0; i < 4; ++i)
#pragma unroll
        for (int j = 0; j < 4; ++j) acc[i][j] = fma_t(av[i], bv2[j], acc[i][j]);
    }
    __syncthreads();
  }
  T* Cp = C + (size_t)blockIdx.z * M * N;
#pragma unroll
  for (int i = 0; i < 4; ++i) {
    const int row = m0 + ty * 4 + i;
#pragma unroll
    for (int j = 0; j < 4; ++j) {
      const int col = n0 + tx * 4 + j;
      T v = acc[i][j];
      if (BIAS) v += (T)bias[col];
      if (RELU) v = v > (T)0 ? v : (T)0;
      Cp[(size_t)row * N + col] = v;
    }
  }
}

// split-K=2 reduction + bias (fp64, deterministic)
__global__ __launch_bounds__(256) void reduce2_bias_kernel(const double* __restrict__ part,
                                                           const float* __restrict__ bias,
                                                           double* __restrict__ out,
                                                           const int MN, const int N) {
  const int i = blockIdx.x * 256 + threadIdx.x;
  if (i < MN) out[i] = part[i] + part[MN + i] + (double)bias[i % N];
}

// ---------------------------------------------------------------------------
// K5: prefill — one block per batch element. Full 4-layer pass in LDS (fp64),
// fills KV caches at positions [0,32). Layer 3: k/v projections only.
// ---------------------------------------------------------------------------
__global__ __launch_bounds__(256) void prefill_kernel(
    const double* __restrict__ toks,
    const float* __restrict__ lnq_g, const float* __restrict__ lnq_b,
    const float* __restrict__ Wq, const float* __restrict__ bq,
    const float* __restrict__ lnk_g, const float* __restrict__ lnk_b,
    const float* __restrict__ Wk, const float* __restrict__ bk,
    const float* __restrict__ lnv_g, const float* __restrict__ lnv_b,
    const float* __restrict__ Wv, const float* __restrict__ bvv,
    const float* __restrict__ Wo, const float* __restrict__ bo,
    const float* __restrict__ mln_g, const float* __restrict__ mln_b,
    const float* __restrict__ W1, const float* __restrict__ b1,
    const float* __restrict__ W2, const float* __restrict__ b2,
    double* __restrict__ kcache, double* __restrict__ vcache) {
  const int b = blockIdx.x, tid = threadIdx.x;
  __shared__ double xcur[1536], abuf[1536], qbuf[1536], kvbuf[3072];
  __shared__ double mean[32], rstd[32];
  double* kb = kvbuf;
  double* vb = kvbuf + 1536;

  for (int i = tid; i < 1536; i += 256) xcur[i] = toks[(size_t)b * 1536 + i];
  __syncthreads();

  for (int l = 0; l < 4; ++l) {
    if (tid < 32) {
      double s = 0.0, s2 = 0.0;
      for (int i = 0; i < 48; ++i) { const double v = xcur[tid * 48 + i]; s += v; s2 += v * v; }
      const double m = s / 48.0;
      mean[tid] = m;
      rstd[tid] = 1.0 / sqrt(s2 / 48.0 - m * m + 1e-5);
    }
    __syncthreads();
    const bool last = (l == 3);

    if (!last) {  // q projection
      for (int i = tid; i < 1536; i += 256) {
        const int t = i / 48, d = i % 48;
        abuf[i] = (xcur[i] - mean[t]) * rstd[t] * (double)lnq_g[l * 48 + d] + (double)lnq_b[l * 48 + d];
      }
      __syncthreads();
      for (int i = tid; i < 1536; i += 256) {
        const int t = i / 48, j = i % 48;
        double acc = (double)bq[l * 48 + j];
        const double* arow = abuf + t * 48;
        const float* wp = Wq + l * 2304 + j;
        for (int kk = 0; kk < 48; ++kk) acc = fma(arow[kk], (double)wp[kk * 48], acc);
        qbuf[i] = acc;
      }
      __syncthreads();
    }
    // k projection
    for (int i = tid; i < 1536; i += 256) {
      const int t = i / 48, d = i % 48;
      abuf[i] = (xcur[i] - mean[t]) * rstd[t] * (double)lnk_g[l * 48 + d] + (double)lnk_b[l * 48 + d];
    }
    __syncthreads();
    for (int i = tid; i < 1536; i += 256) {
      const int t = i / 48, j = i % 48;
      double acc = (double)bk[l * 48 + j];
      const double* arow = abuf + t * 48;
      const float* wp = Wk + l * 2304 + j;
      for (int kk = 0; kk < 48; ++kk) acc = fma(arow[kk], (double)wp[kk * 48], acc);
      kb[i] = acc;
    }
    __syncthreads();
    // v projection
    for (int i = tid; i < 1536; i += 256) {
      const int t = i / 48, d = i % 48;
      abuf[i] = (xcur[i] - mean[t]) * rstd[t] * (double)lnv_g[l * 48 + d] + (double)lnv_b[l * 48 + d];
    }
    __syncthreads();
    for (int i = tid; i < 1536; i += 256) {
      const int t = i / 48, j = i % 48;
      double acc = (double)bvv[l * 48 + j];
      const double* arow = abuf + t * 48;
      const float* wp = Wv + l * 2304 + j;
      for (int kk = 0; kk < 48; ++kk) acc = fma(arow[kk], (double)wp[kk * 48], acc);
      vb[i] = acc;
    }
    __syncthreads();
    // store k,v to cache at pos t
    for (int i = tid; i < 1536; i += 256) {
      const int t = i / 48, j = i % 48;
      const int h = j / 6, d = j % 6;
      const size_t ci = ((((size_t)b * 4 + l) * 8 + h) * 64 + t) * 6 + d;
      kcache[ci] = kb[i];
      vcache[ci] = vb[i];
    }

    if (!last) {
      // attention: thread = (token t, head h). mask only (t=0, j=31).
      const int t = tid >> 3, h = tid & 7;
      const double* qp = qbuf + t * 48 + h * 6;
      const double q0 = qp[0], q1 = qp[1], q2 = qp[2], q3 = qp[3], q4 = qp[4], q5 = qp[5];
      double mx = -1e300;
      for (int j = 0; j < 32; ++j) {
        const double* kp = kb + j * 48 + h * 6;
        double sv = q0 * kp[0];
        sv = fma(q1, kp[1], sv); sv = fma(q2, kp[2], sv); sv = fma(q3, kp[3], sv);
        sv = fma(q4, kp[4], sv); sv = fma(q5, kp[5], sv);
        sv /= SCALE_;
        if (t == 0 && j == 31) sv -= 999.0;
        mx = sv > mx ? sv : mx;
      }
      double den = 0, o0 = 0, o1 = 0, o2 = 0, o3 = 0, o4 = 0, o5 = 0;
      for (int j = 0; j < 32; ++j) {
        const double* kp = kb + j * 48 + h * 6;
        double sv = q0 * kp[0];
        sv = fma(q1, kp[1], sv); sv = fma(q2, kp[2], sv); sv = fma(q3, kp[3], sv);
        sv = fma(q4, kp[4], sv); sv = fma(q5, kp[5], sv);
        sv /= SCALE_;
        if (t == 0 && j == 31) sv -= 999.0;
        const double e = exp(sv - mx);
        den += e;
        const double* vp = vb + j * 48 + h * 6;
        o0 = fma(e, vp[0], o0); o1 = fma(e, vp[1], o1); o2 = fma(e, vp[2], o2);
        o3 = fma(e, vp[3], o3); o4 = fma(e, vp[4], o4); o5 = fma(e, vp[5], o5);
      }
      abuf[t * 48 + h * 6 + 0] = o0 / den;
      abuf[t * 48 + h * 6 + 1] = o1 / den;
      abuf[t * 48 + h * 6 + 2] = o2 / den;
      abuf[t * 48 + h * 6 + 3] = o3 / den;
      abuf[t * 48 + h * 6 + 4] = o4 / den;
      abuf[t * 48 + h * 6 + 5] = o5 / den;
      __syncthreads();
      // Wo + residual
      for (int i = tid; i < 1536; i += 256) {
        const int t2 = i / 48, j = i % 48;
        double acc = (double)bo[l * 48 + j];
        const double* orow = abuf + t2 * 48;
        const float* wp = Wo + l * 2304 + j;
        for (int kk = 0; kk < 48; ++kk) acc = fma(orow[kk], (double)wp[kk * 48], acc);
        xcur[i] = acc + xcur[i];
      }
      __syncthreads();
      // MLP LN
      if (tid < 32) {
        double s = 0.0, s2 = 0.0;
        for (int i = 0; i < 48; ++i) { const double v = xcur[tid * 48 + i]; s += v; s2 += v * v; }
        const double m = s / 48.0;
        mean[tid] = m;
        rstd[tid] = 1.0 / sqrt(s2 / 48.0 - m * m + 1e-5);
      }
      __syncthreads();
      for (int i = tid; i < 1536; i += 256) {
        const int t2 = i / 48, d = i % 48;
        qbuf[i] = (xcur[i] - mean[t2]) * rstd[t2] * (double)mln_g[l * 48 + d] + (double)mln_b[l * 48 + d];
      }
      __syncthreads();
      for (int i = tid; i < 3072; i += 256) {
        const int t2 = i / 96, jj = i % 96;
        double acc = (double)b1[l * 96 + jj];
        const double* arow = qbuf + t2 * 48;
        const float* wp = W1 + l * 4608 + jj;
        for (int kk = 0; kk < 48; ++kk) acc = fma(arow[kk], (double)wp[kk * 96], acc);
        kvbuf[i] = acc > 0 ? acc : 0;
      }
      __syncthreads();
      for (int i = tid; i < 1536; i += 256) {
        const int t2 = i / 48, j = i % 48;
        double acc = (double)b2[l * 48 + j];
        const double* hrow = kvbuf + t2 * 96;
        const float* wp = W2 + l * 4608 + j;
        for (int kk = 0; kk < 96; ++kk) acc = fma(hrow[kk], (double)wp[kk * 48], acc);
        abuf[i] = acc;  // no residual
      }
      __syncthreads();
      for (int i = tid; i < 1536; i += 256) xcur[i] = abuf[i];
      __syncthreads();
    }
  }
}

// ---------------------------------------------------------------------------
// K6: autoregressive loop — one block of 256 threads (4 waves) per batch
// element. All 32 steps x 4 layers in-kernel. fp64 throughout.
// ---------------------------------------------------------------------------
__global__ __launch_bounds__(256) void ar_kernel(
    const float* __restrict__ pos_enc, const float* __restrict__ u,
    const float* __restrict__ lnq_g, const float* __restrict__ lnq_b,
    const float* __restrict__ Wq, const float* __restrict__ bq,
    const float* __restrict__ lnk_g, const float* __restrict__ lnk_b,
    const float* __restrict__ Wk, const float* __restrict__ bk,
    const float* __restrict__ lnv_g, const float* __restrict__ lnv_b,
    const float* __restrict__ Wv, const float* __restrict__ bvv,
    const float* __restrict__ Wo, const float* __restrict__ bo,
    const float* __restrict__ mln_g, const float* __restrict__ mln_b,
    const float* __restrict__ W1, const float* __restrict__ b1,
    const float* __restrict__ W2, const float* __restrict__ b2,
    const float* __restrict__ emb,
    double* __restrict__ kcache, double* __restrict__ vcache,
    float* __restrict__ out_tok) {
  const int b = blockIdx.x, tid = threadIdx.x;
  __shared__ double xtk[48], anorm[144], qs[48], os[48], hh[96], probs[512], red[4];

  for (int step = 0; step < 32; ++step) {
    const int p = 32 + step;
    if (tid < 48) xtk[tid] = (double)pos_enc[step * 48 + tid];
    __syncthreads();

    for (int l = 0; l < 4; ++l) {
      // ---- LN stats (computed redundantly by all threads; LDS broadcast) ----
      {
        double s0 = 0, s1 = 0, q0 = 0, q1 = 0;
#pragma unroll
        for (int i = 0; i < 48; i += 2) {
          const double va = xtk[i], vb2 = xtk[i + 1];
          s0 += va; q0 = fma(va, va, q0);
          s1 += vb2; q1 = fma(vb2, vb2, q1);
        }
        const double m = (s0 + s1) / 48.0;
        const double rs = 1.0 / sqrt((q0 + q1) / 48.0 - m * m + 1e-5);
        if (tid < 144) {
          const int which = tid / 48, d = tid - which * 48;
          const float* gp = which == 0 ? lnq_g : which == 1 ? lnk_g : lnv_g;
          const float* bp = which == 0 ? lnq_b : which == 1 ? lnk_b : lnv_b;
          anorm[tid] = (xtk[d] - m) * rs * (double)gp[l * 48 + d] + (double)bp[l * 48 + d];
        }
      }
      __syncthreads();
      // ---- q,k,v projections: 144 threads, one output each ----
      if (tid < 144) {
        const int which = tid / 48, j = tid - which * 48;
        const float* Wb = which == 0 ? Wq : which == 1 ? Wk : Wv;
        const float* bbp = which == 0 ? bq : which == 1 ? bk : bvv;
        const double* an = anorm + which * 48;
        double a0 = (double)bbp[l * 48 + j], a1 = 0.0;
        const float* wp = Wb + l * 2304 + j;
#pragma unroll
        for (int i = 0; i < 48; i += 2) {
          a0 = fma(an[i],     (double)wp[i * 48],       a0);
          a1 = fma(an[i + 1], (double)wp[(i + 1) * 48], a1);
        }
        const double acc = a0 + a1;
        if (which == 0) {
          qs[j] = acc;
        } else {
          const int h = j / 6, d = j - h * 6;
          const size_t ci = ((((size_t)b * 4 + l) * 8 + h) * 64 + p) * 6 + d;
          if (which == 1) kcache[ci] = acc; else vcache[ci] = acc;
        }
      }
      __syncthreads();
      // ---- attention over [0,p): 32 lanes per head, <=2 positions each ----
      {
        const int h = tid >> 5, r = tid & 31;
        const double* kcb = kcache + ((((size_t)b * 4 + l) * 8 + h) * 64) * 6;
        const double* vcb = vcache + ((((size_t)b * 4 + l) * 8 + h) * 64) * 6;
        const double qv0 = qs[h * 6 + 0], qv1 = qs[h * 6 + 1], qv2 = qs[h * 6 + 2],
                     qv3 = qs[h * 6 + 3], qv4 = qs[h * 6 + 4], qv5 = qs[h * 6 + 5];
        const bool has2 = (r + 32) < p;
        const double* kp1 = kcb + r * 6;
        double sv1 = qv0 * kp1[0];
        sv1 = fma(qv1, kp1[1], sv1); sv1 = fma(qv2, kp1[2], sv1); sv1 = fma(qv3, kp1[3], sv1);
        sv1 = fma(qv4, kp1[4], sv1); sv1 = fma(qv5, kp1[5], sv1);
        sv1 /= SCALE_;
        double sv2 = -1e300;
        if (has2) {
          const double* kp2 = kcb + (r + 32) * 6;
          double t2 = qv0 * kp2[0];
          t2 = fma(qv1, kp2[1], t2); t2 = fma(qv2, kp2[2], t2); t2 = fma(qv3, kp2[3], t2);
          t2 = fma(qv4, kp2[4], t2); t2 = fma(qv5, kp2[5], t2);
          sv2 = t2 / SCALE_;
        }
        double mx = sv1 > sv2 ? sv1 : sv2;
#pragma unroll
        for (int off = 1; off < 32; off <<= 1) { const double o2 = __shfl_xor(mx, off); mx = o2 > mx ? o2 : mx; }
        const double e1 = exp(sv1 - mx);
        const double e2 = has2 ? exp(sv2 - mx) : 0.0;
        double den = e1 + e2;
        const double* vp1 = vcb + r * 6;
        double o[6];
#pragma unroll
        for (int d = 0; d < 6; ++d) o[d] = e1 * vp1[d];
        if (has2) {
          const double* vp2 = vcb + (r + 32) * 6;
#pragma unroll
          for (int d = 0; d < 6; ++d) o[d] = fma(e2, vp2[d], o[d]);
        }
#pragma unroll
        for (int off = 1; off < 32; off <<= 1) {
          den += __shfl_xor(den, off);
#pragma unroll
          for (int d = 0; d < 6; ++d) o[d] += __shfl_xor(o[d], off);
        }
        if (r == 0) {
#pragma unroll
          for (int d = 0; d < 6; ++d) os[h * 6 + d] = o[d] / den;
        }
      }
      __syncthreads();
      // ---- Wo + residual ----
      if (tid < 48) {
        double a0 = (double)bo[l * 48 + tid], a1 = 0.0;
        const float* wp = Wo + l * 2304 + tid;
#pragma unroll
        for (int i = 0; i < 48; i += 2) {
          a0 = fma(os[i],     (double)wp[i * 48],       a0);
          a1 = fma(os[i + 1], (double)wp[(i + 1) * 48], a1);
        }
        xtk[tid] = a0 + a1 + xtk[tid];
      }
      __syncthreads();
      // ---- MLP LN (redundant stats) ----
      {
        double s0 = 0, s1 = 0, q0 = 0, q1 = 0;
#pragma unroll
        for (int i = 0; i < 48; i += 2) {
          const double va = xtk[i], vb2 = xtk[i + 1];
          s0 += va; q0 = fma(va, va, q0);
          s1 += vb2; q1 = fma(vb2, vb2, q1);
        }
        const double m = (s0 + s1) / 48.0;
        const double rs = 1.0 / sqrt((q0 + q1) / 48.0 - m * m + 1e-5);
        if (tid < 48)
          anorm[tid] = (xtk[tid] - m) * rs * (double)mln_g[l * 48 + tid] + (double)mln_b[l * 48 + tid];
      }
      __syncthreads();
      // ---- MLP1 (96 outputs) ----
      if (tid < 96) {
        double a0 = (double)b1[l * 96 + tid], a1 = 0.0;
        const float* wp = W1 + l * 4608 + tid;
#pragma unroll
        for (int i = 0; i < 48; i += 2) {
          a0 = fma(anorm[i],     (double)wp[i * 96],       a0);
          a1 = fma(anorm[i + 1], (double)wp[(i + 1) * 96], a1);
        }
        const double v = a0 + a1;
        hh[tid] = v > 0 ? v : 0;
      }
      __syncthreads();
      // ---- MLP2 (48 outputs, no residual) ----
      if (tid < 48) {
        double a0 = (double)b2[l * 48 + tid], a1 = 0.0;
        const float* wp = W2 + l * 4608 + tid;
#pragma unroll
        for (int i = 0; i < 96; i += 2) {
          a0 = fma(hh[i],     (double)wp[i * 48],       a0);
          a1 = fma(hh[i + 1], (double)wp[(i + 1) * 48], a1);
        }
        xtk[tid] = a0 + a1;
      }
      __syncthreads();
    }

    // ---- sampling: logits by 256 threads (2 each), fp64 softmax + scan ----
    {
      double lg1 = 0, lg2 = 0;
#pragma unroll
      for (int d0 = 0; d0 < 48; ++d0) {
        const double xv = xtk[d0];
        lg1 = fma(xv, (double)emb[d0 * 512 + tid], lg1);
        lg2 = fma(xv, (double)emb[d0 * 512 + 256 + tid], lg2);
      }
      double mx = lg1 > lg2 ? lg1 : lg2;
#pragma unroll
      for (int off = 1; off < 64; off <<= 1) { const double o2 = __shfl_xor(mx, off); mx = o2 > mx ? o2 : mx; }
      if ((tid & 63) == 0) red[tid >> 6] = mx;
      __syncthreads();
      {
        const double m0 = red[0] > red[1] ? red[0] : red[1];
        const double m1 = red[2] > red[3] ? red[2] : red[3];
        mx = m0 > m1 ? m0 : m1;
      }
      probs[tid] = exp(lg1 - mx);
      probs[tid + 256] = exp(lg2 - mx);
    }
    __syncthreads();
    if (tid < 64) {
      const int lane = tid;
      double loc[8], run = 0;
#pragma unroll
      for (int n2 = 0; n2 < 8; ++n2) { run += probs[lane * 8 + n2]; loc[n2] = run; }
      double incl = run;
      for (int off = 1; off < 64; off <<= 1) {
        const double t2 = __shfl_up(incl, off);
        if (lane >= off) incl += t2;
      }
      const double excl = incl - run;
      const double Ssum = __shfl(incl, 63);
      const double uu = (double)u[step * 512 + b];
      int cnt = 0;
#pragma unroll
      for (int n2 = 0; n2 < 8; ++n2) cnt += ((excl + loc[n2]) / Ssum < uu) ? 1 : 0;
#pragma unroll
      for (int off = 1; off < 64; off <<= 1) cnt += __shfl_xor(cnt, off);
      const int idx = cnt > 511 ? 511 : cnt;
      if (lane < 48) {
        const double sel = (double)emb[lane * 512 + idx];
        const double att = xtk[lane];
        out_tok[(size_t)b * 1536 + step * 48 + lane] = (float)((sel + att) - att);  // straight-through fwd
      }
    }
    __syncthreads();
  }
}

// ---------------------------------------------------------------------------
// Launch
// ---------------------------------------------------------------------------
extern "C" void kernel_launch(void* const* d_in, const int* in_sizes, int n_in,
                              void* d_out, int out_size, void* d_ws, size_t ws_size,
                              hipStream_t stream) {
  const float* x      = (const float*)d_in[0];
  const float* u      = (const float*)d_in[1];
  const float* bn_g   = (const float*)d_in[2];
  const float* bn_b   = (const float*)d_in[3];
  const float* conv_w = (const float*)d_in[4];
  const float* conv_b = (const float*)d_in[5];
  const float* tk_W1  = (const float*)d_in[6];
  const float* tk_b1  = (const float*)d_in[7];
  const float* tk_W2  = (const float*)d_in[8];
  const float* tk_b2  = (const float*)d_in[9];
  const float* lnq_g  = (const float*)d_in[10];
  const float* lnq_b  = (const float*)d_in[11];
  const float* Wq     = (const float*)d_in[12];
  const float* bq     = (const float*)d_in[13];
  const float* lnk_g  = (const float*)d_in[14];
  const float* lnk_b  = (const float*)d_in[15];
  const float* Wk     = (const float*)d_in[16];
  const float* bk     = (const float*)d_in[17];
  const float* lnv_g  = (const float*)d_in[18];
  const float* lnv_b  = (const float*)d_in[19];
  const float* Wv     = (const float*)d_in[20];
  const float* bvv    = (const float*)d_in[21];
  const float* Wo     = (const float*)d_in[22];
  const float* bo     = (const float*)d_in[23];
  const float* mln_g  = (const float*)d_in[24];
  const float* mln_b  = (const float*)d_in[25];
  const float* W1     = (const float*)d_in[26];
  const float* b1     = (const float*)d_in[27];
  const float* W2     = (const float*)d_in[28];
  const float* b2     = (const float*)d_in[29];
  const float* emb    = (const float*)d_in[30];
  const float* pos    = (const float*)d_in[31];
  const float* dW1    = (const float*)d_in[32];
  const float* db1    = (const float*)d_in[33];
  const float* dW2    = (const float*)d_in[34];
  const float* db2    = (const float*)d_in[35];
  float* out = (float*)d_out;

  char* w = (char*)d_ws;
  size_t off = 0;
  auto alloc = [&](size_t bytes) {
    size_t o = off;
    off = (off + bytes + 255) & ~(size_t)255;
    return o;
  };
  const size_t o_bnp  = alloc(512 * 14 * 8);
  const size_t o_bns  = alloc(14 * 8);
  const size_t o_xf   = alloc(16777216);   // xf fp64; later reused for split-K partials (12.6MB)
  const size_t o_h    = alloc(33554432);   // h fp64; later reused for out_tok(3.1MB)+dh(6.3MB)
  const size_t o_toks = alloc(6291456);
  const size_t o_kc   = alloc(50331648);
  const size_t o_vc   = alloc(50331648);

  double* bnp  = (double*)(w + o_bnp);
  double* bns  = (double*)(w + o_bns);
  double* xf   = (double*)(w + o_xf);
  double* hbuf = (double*)(w + o_h);
  double* toks = (double*)(w + o_toks);
  double* kc   = (double*)(w + o_kc);
  double* vc   = (double*)(w + o_vc);
  double* part = (double*)(w + o_xf);                 // reuse (xf dead after G1)
  float*  otok = (float*)(w + o_h);                   // reuse (h dead after G2)
  float*  dh   = (float*)(w + o_h + 4194304);

  // 1-2: BatchNorm stats (deterministic fp64)
  bn_partial_kernel<<<512, 256, 0, stream>>>(x, bnp);
  bn_final_kernel<<<1, 64, 0, stream>>>(bnp, bn_g, bn_b, bns);
  // 3: BN-apply + conv + flatten -> xf [512,4096]
  conv_kernel<<<8192, 256, 0, stream>>>(x, conv_w, conv_b, bns, xf);
  // 4: h = relu(xf @ tk_W1 + b1)  [512,8192]
  gemm_kernel<double, true, true><<<dim3(128, 8, 1), 256, 0, stream>>>(
      xf, tk_W1, tk_b1, hbuf, 512, 8192, 4096, 4096);
  // 5: toks = h @ tk_W2 + b2 (split-K=2 into partials, then reduce)
  gemm_kernel<double, false, false><<<dim3(24, 8, 2), 256, 0, stream>>>(
      hbuf, tk_W2, nullptr, part, 512, 1536, 8192, 4096);
  reduce2_bias_kernel<<<3072, 256, 0, stream>>>(part, tk_b2, toks, 512 * 1536, 1536);
  // 6: prefill (fills KV caches, positions 0..31)
  prefill_kernel<<<512, 256, 0, stream>>>(toks,
      lnq_g, lnq_b, Wq, bq, lnk_g, lnk_b, Wk, bk, lnv_g, lnv_b, Wv, bvv,
      Wo, bo, mln_g, mln_b, W1, b1, W2, b2, kc, vc);
  // 7: autoregressive loop (32 steps x 4 layers, 256 threads per batch elem)
  ar_kernel<<<512, 256, 0, stream>>>(pos, u,
      lnq_g, lnq_b, Wq, bq, lnk_g, lnk_b, Wk, bk, lnv_g, lnv_b, Wv, bvv,
      Wo, bo, mln_g, mln_b, W1, b1, W2, b2, emb, kc, vc, otok);
  // 8: decoder (fp32 — post-sampling, continuous path)
  gemm_kernel<float, true, true><<<dim3(48, 8, 1), 256, 0, stream>>>(
      otok, dW1, db1, dh, 512, 3072, 1536, 1536);
  gemm_kernel<float, true, false><<<dim3(28, 8, 1), 256, 0, stream>>>(
      dh, dW2, db2, out, 512, 1792, 3072, 3072);
}

// Round 3
// 7203.266 us; speedup vs baseline: 2.3513x; 1.9149x over previous
//
#include <hip/hip_runtime.h>

// ---------------------------------------------------------------------------
// Dims
// ---------------------------------------------------------------------------
// B=512 A=256 CIN=7 CC=16 D=48 H=8 DH=6 E=512 S=32 T=32 NL=4 STOT=64
// CONV_IN=4096 HID=8192 ENC=1536 DEC_HID=3072 DEC_OUT=1792
static const double SCALE_ = 6.928203230275509;  // sqrt(48)

__device__ inline float  fma_t(float a, float b, float c)  { return fmaf(a, b, c); }
__device__ inline double fma_t(double a, double b, double c){ return fma(a, b, c); }

// ---------------------------------------------------------------------------
// Shared compact helpers (deduped code — ar_kernel must stay I$-resident)
// ---------------------------------------------------------------------------
// y = init + sum_{i<n} a[i] * W[i*ldw]   (dual accumulator, pairing matches R2)
__device__ __attribute__((noinline)) double dotW(const double* a,
                                                 const float* W, int n, int ldw,
                                                 double init) {
  double a0 = init, a1 = 0.0;
#pragma unroll 2
  for (int i = 0; i < n; i += 2) {
    a0 = fma(a[i],     (double)W[i * ldw],       a0);
    a1 = fma(a[i + 1], (double)W[(i + 1) * ldw], a1);
  }
  return a0 + a1;
}

// LayerNorm stats over 48 elements (redundant per-thread; pairing matches R2)
__device__ __attribute__((noinline)) double2 ln_stats48(const double* x) {
  double s0 = 0, s1 = 0, q0 = 0, q1 = 0;
#pragma unroll 2
  for (int i = 0; i < 48; i += 2) {
    const double va = x[i], vb = x[i + 1];
    s0 += va; q0 = fma(va, va, q0);
    s1 += vb; q1 = fma(vb, vb, q1);
  }
  const double m = (s0 + s1) / 48.0;
  const double rs = 1.0 / sqrt((q0 + q1) / 48.0 - m * m + 1e-5);
  return make_double2(m, rs);
}

__device__ __attribute__((noinline)) double exp_ni(double x) { return exp(x); }

// ---------------------------------------------------------------------------
// K1: BatchNorm partial sums (deterministic, fp64)
// ---------------------------------------------------------------------------
__global__ __launch_bounds__(256) void bn_partial_kernel(const float* __restrict__ x,
                                                         double* __restrict__ part) {
  __shared__ double sh[256 * 14];
  const int tid = threadIdx.x;
  const int idx = blockIdx.x * 256 + tid;  // (b,a) pair, 0..131071
  const float* p = x + (size_t)idx * 7;
  for (int c = 0; c < 7; ++c) {
    double v = (double)p[c];
    sh[tid * 14 + c] = v;
    sh[tid * 14 + 7 + c] = v * v;
  }
  __syncthreads();
  if (tid < 14) {
    double acc = 0.0;
    for (int t = 0; t < 256; ++t) acc += sh[t * 14 + tid];
    part[blockIdx.x * 14 + tid] = acc;
  }
}

// K2: finalize BN stats -> per-channel scale/shift (fp64)
__global__ void bn_final_kernel(const double* __restrict__ part,
                                const float* __restrict__ g, const float* __restrict__ bb,
                                double* __restrict__ stat) {
  const int c = threadIdx.x;
  if (c < 7) {
    double s = 0.0, s2 = 0.0;
    for (int i = 0; i < 512; ++i) { s += part[i * 14 + c]; s2 += part[i * 14 + 7 + c]; }
    const double mean = s / 131072.0;
    const double var = s2 / 131072.0 - mean * mean;
    const double rstd = 1.0 / sqrt(var + 1e-5);
    const double scale = rstd * (double)g[c];
    stat[c] = scale;                          // x*scale + shift
    stat[7 + c] = (double)bb[c] - mean * scale;
  }
}

// ---------------------------------------------------------------------------
// K3: BN-apply + Conv1d(7->16,k=5,pad=2) + flatten -> xf [512, 16*256] fp64
// ---------------------------------------------------------------------------
__global__ __launch_bounds__(256) void conv_kernel(const float* __restrict__ x,
                                                   const float* __restrict__ wconv,
                                                   const float* __restrict__ cb,
                                                   const double* __restrict__ stat,
                                                   double* __restrict__ xf) {
  __shared__ double wsh[560 + 14];
  const int tid = threadIdx.x;
  for (int i = tid; i < 560; i += 256) wsh[i] = (double)wconv[i];
  for (int i = tid; i < 14; i += 256) wsh[560 + i] = stat[i];
  __syncthreads();
  const int idx = blockIdx.x * 256 + tid;    // b*4096 + o*256 + a
  const int a = idx & 255;
  const int o = (idx >> 8) & 15;
  const int b = idx >> 12;
  double acc = (double)cb[o];
  const float* xb = x + (size_t)b * (256 * 7);
  for (int k = 0; k < 5; ++k) {
    const int pos = a + k - 2;
    if (pos < 0 || pos >= 256) continue;
    const float* xp = xb + pos * 7;
    for (int ci = 0; ci < 7; ++ci) {
      const double xn = (double)xp[ci] * wsh[560 + ci] + wsh[567 + ci];
      acc = fma(xn, wsh[(o * 7 + ci) * 5 + k], acc);
    }
  }
  xf[idx] = acc;
}

// ---------------------------------------------------------------------------
// Tiled GEMM: C[M,N] = act(A[M,K] @ Bf[K,N] (+bias)); A,C of type T; B fp32.
// BM=BN=64, BK=16, 256 threads, 4x4 microtile. grid.z = split-K chunks.
// ---------------------------------------------------------------------------
template <typename T, bool BIAS, bool RELU>
__global__ __launch_bounds__(256) void gemm_kernel(const T* __restrict__ A,
                                                   const float* __restrict__ Bm,
                                                   const float* __restrict__ bias,
                                                   T* __restrict__ C,
                                                   const int M, const int N, const int K,
                                                   const int kc) {
  __shared__ T As[16][65];
  __shared__ T Bs[16][65];
  const int tid = threadIdx.x;
  const int tx = tid & 15, ty = tid >> 4;
  const int n0 = blockIdx.x * 64, m0 = blockIdx.y * 64;
  const int k0 = blockIdx.z * kc, kend = k0 + kc;
  const int ar = tid >> 2, ac = (tid & 3) * 4;
  const int br = tid >> 4, bc = (tid & 15) * 4;
  const T* Ap = A + (size_t)(m0 + ar) * K;
  const float* Bp = Bm + (size_t)br * N + n0 + bc;
  T acc[4][4] = {};
  for (int k = k0; k < kend; k += 16) {
    const T a0 = Ap[k + ac], a1 = Ap[k + ac + 1], a2 = Ap[k + ac + 2], a3 = Ap[k + ac + 3];
    const float4 bw = *(const float4*)(Bp + (size_t)k * N);
    As[ac][ar] = a0; As[ac + 1][ar] = a1; As[ac + 2][ar] = a2; As[ac + 3][ar] = a3;
    Bs[br][bc] = (T)bw.x; Bs[br][bc + 1] = (T)bw.y; Bs[br][bc + 2] = (T)bw.z; Bs[br][bc + 3] = (T)bw.w;
    __syncthreads();
#pragma unroll
    for (int kk = 0; kk < 16; ++kk) {
      T av[4], bv2[4];
#pragma unroll
      for (int i = 0; i < 4; ++i) av[i] = As[kk][ty * 4 + i];
#pragma unroll
      for (int j = 0; j < 4; ++j) bv2[j] = Bs[kk][tx * 4 + j];
#pragma unroll
      for (int i = 0; i < 4; ++i)
#pragma unroll
        for (int j = 0; j < 4; ++j) acc[i][j] = fma_t(av[i], bv2[j], acc[i][j]);
    }
    __syncthreads();
  }
  T* Cp = C + (size_t)blockIdx.z * M * N;
#pragma unroll
  for (int i = 0; i < 4; ++i) {
    const int row = m0 + ty * 4 + i;
#pragma unroll
    for (int j = 0; j < 4; ++j) {
      const int col = n0 + tx * 4 + j;
      T v = acc[i][j];
      if (BIAS) v += (T)bias[col];
      if (RELU) v = v > (T)0 ? v : (T)0;
      Cp[(size_t)row * N + col] = v;
    }
  }
}

// split-K=2 reduction + bias (fp64, deterministic)
__global__ __launch_bounds__(256) void reduce2_bias_kernel(const double* __restrict__ part,
                                                           const float* __restrict__ bias,
                                                           double* __restrict__ out,
                                                           const int MN, const int N) {
  const int i = blockIdx.x * 256 + threadIdx.x;
  if (i < MN) out[i] = part[i] + part[MN + i] + (double)bias[i % N];
}

// ---------------------------------------------------------------------------
// K5: prefill — one block per batch element. Full 4-layer pass in LDS (fp64),
// fills KV caches at positions [0,32). Layer 3: k/v projections only.
// Compact code (dotW + capped unrolls) to stay I$-resident.
// ---------------------------------------------------------------------------
__global__ __launch_bounds__(256) void prefill_kernel(
    const double* __restrict__ toks,
    const float* __restrict__ lnq_g, const float* __restrict__ lnq_b,
    const float* __restrict__ Wq, const float* __restrict__ bq,
    const float* __restrict__ lnk_g, const float* __restrict__ lnk_b,
    const float* __restrict__ Wk, const float* __restrict__ bk,
    const float* __restrict__ lnv_g, const float* __restrict__ lnv_b,
    const float* __restrict__ Wv, const float* __restrict__ bvv,
    const float* __restrict__ Wo, const float* __restrict__ bo,
    const float* __restrict__ mln_g, const float* __restrict__ mln_b,
    const float* __restrict__ W1, const float* __restrict__ b1,
    const float* __restrict__ W2, const float* __restrict__ b2,
    double* __restrict__ kcache, double* __restrict__ vcache) {
  const int b = blockIdx.x, tid = threadIdx.x;
  __shared__ double xcur[1536], abuf[1536], qbuf[1536], kvbuf[3072];
  __shared__ double mean[32], rstd[32];
  double* kb = kvbuf;
  double* vb = kvbuf + 1536;

#pragma unroll 1
  for (int i = tid; i < 1536; i += 256) xcur[i] = toks[(size_t)b * 1536 + i];
  __syncthreads();

#pragma unroll 1
  for (int l = 0; l < 4; ++l) {
    if (tid < 32) {
      double s = 0.0, s2 = 0.0;
#pragma unroll 4
      for (int i = 0; i < 48; ++i) { const double v = xcur[tid * 48 + i]; s += v; s2 += v * v; }
      const double m = s / 48.0;
      mean[tid] = m;
      rstd[tid] = 1.0 / sqrt(s2 / 48.0 - m * m + 1e-5);
    }
    __syncthreads();
    const bool last = (l == 3);

    if (!last) {  // q projection
#pragma unroll 1
      for (int i = tid; i < 1536; i += 256) {
        const int t = i / 48, d = i % 48;
        abuf[i] = (xcur[i] - mean[t]) * rstd[t] * (double)lnq_g[l * 48 + d] + (double)lnq_b[l * 48 + d];
      }
      __syncthreads();
#pragma unroll 1
      for (int i = tid; i < 1536; i += 256) {
        const int t = i / 48, j = i % 48;
        qbuf[i] = dotW(abuf + t * 48, Wq + l * 2304 + j, 48, 48, (double)bq[l * 48 + j]);
      }
      __syncthreads();
    }
    // k projection
#pragma unroll 1
    for (int i = tid; i < 1536; i += 256) {
      const int t = i / 48, d = i % 48;
      abuf[i] = (xcur[i] - mean[t]) * rstd[t] * (double)lnk_g[l * 48 + d] + (double)lnk_b[l * 48 + d];
    }
    __syncthreads();
#pragma unroll 1
    for (int i = tid; i < 1536; i += 256) {
      const int t = i / 48, j = i % 48;
      kb[i] = dotW(abuf + t * 48, Wk + l * 2304 + j, 48, 48, (double)bk[l * 48 + j]);
    }
    __syncthreads();
    // v projection
#pragma unroll 1
    for (int i = tid; i < 1536; i += 256) {
      const int t = i / 48, d = i % 48;
      abuf[i] = (xcur[i] - mean[t]) * rstd[t] * (double)lnv_g[l * 48 + d] + (double)lnv_b[l * 48 + d];
    }
    __syncthreads();
#pragma unroll 1
    for (int i = tid; i < 1536; i += 256) {
      const int t = i / 48, j = i % 48;
      vb[i] = dotW(abuf + t * 48, Wv + l * 2304 + j, 48, 48, (double)bvv[l * 48 + j]);
    }
    __syncthreads();
    // store k,v to cache at pos t
#pragma unroll 1
    for (int i = tid; i < 1536; i += 256) {
      const int t = i / 48, j = i % 48;
      const int h = j / 6, d = j % 6;
      const size_t ci = ((((size_t)b * 4 + l) * 8 + h) * 64 + t) * 6 + d;
      kcache[ci] = kb[i];
      vcache[ci] = vb[i];
    }

    if (!last) {
      // attention: thread = (token t, head h). mask only (t=0, j=31).
      const int t = tid >> 3, h = tid & 7;
      const double* qp = qbuf + t * 48 + h * 6;
      const double q0 = qp[0], q1 = qp[1], q2 = qp[2], q3 = qp[3], q4 = qp[4], q5 = qp[5];
      double mx = -1e300;
#pragma unroll 4
      for (int j = 0; j < 32; ++j) {
        const double* kp = kb + j * 48 + h * 6;
        double sv = q0 * kp[0];
        sv = fma(q1, kp[1], sv); sv = fma(q2, kp[2], sv); sv = fma(q3, kp[3], sv);
        sv = fma(q4, kp[4], sv); sv = fma(q5, kp[5], sv);
        sv /= SCALE_;
        if (t == 0 && j == 31) sv -= 999.0;
        mx = sv > mx ? sv : mx;
      }
      double den = 0, o0 = 0, o1 = 0, o2 = 0, o3 = 0, o4 = 0, o5 = 0;
#pragma unroll 4
      for (int j = 0; j < 32; ++j) {
        const double* kp = kb + j * 48 + h * 6;
        double sv = q0 * kp[0];
        sv = fma(q1, kp[1], sv); sv = fma(q2, kp[2], sv); sv = fma(q3, kp[3], sv);
        sv = fma(q4, kp[4], sv); sv = fma(q5, kp[5], sv);
        sv /= SCALE_;
        if (t == 0 && j == 31) sv -= 999.0;
        const double e = exp_ni(sv - mx);
        den += e;
        const double* vp = vb + j * 48 + h * 6;
        o0 = fma(e, vp[0], o0); o1 = fma(e, vp[1], o1); o2 = fma(e, vp[2], o2);
        o3 = fma(e, vp[3], o3); o4 = fma(e, vp[4], o4); o5 = fma(e, vp[5], o5);
      }
      abuf[t * 48 + h * 6 + 0] = o0 / den;
      abuf[t * 48 + h * 6 + 1] = o1 / den;
      abuf[t * 48 + h * 6 + 2] = o2 / den;
      abuf[t * 48 + h * 6 + 3] = o3 / den;
      abuf[t * 48 + h * 6 + 4] = o4 / den;
      abuf[t * 48 + h * 6 + 5] = o5 / den;
      __syncthreads();
      // Wo + residual
#pragma unroll 1
      for (int i = tid; i < 1536; i += 256) {
        const int t2 = i / 48, j = i % 48;
        xcur[i] += dotW(abuf + t2 * 48, Wo + l * 2304 + j, 48, 48, (double)bo[l * 48 + j]);
      }
      __syncthreads();
      // MLP LN
      if (tid < 32) {
        double s = 0.0, s2 = 0.0;
#pragma unroll 4
        for (int i = 0; i < 48; ++i) { const double v = xcur[tid * 48 + i]; s += v; s2 += v * v; }
        const double m = s / 48.0;
        mean[tid] = m;
        rstd[tid] = 1.0 / sqrt(s2 / 48.0 - m * m + 1e-5);
      }
      __syncthreads();
#pragma unroll 1
      for (int i = tid; i < 1536; i += 256) {
        const int t2 = i / 48, d = i % 48;
        qbuf[i] = (xcur[i] - mean[t2]) * rstd[t2] * (double)mln_g[l * 48 + d] + (double)mln_b[l * 48 + d];
      }
      __syncthreads();
#pragma unroll 1
      for (int i = tid; i < 3072; i += 256) {
        const int t2 = i / 96, jj = i % 96;
        const double acc = dotW(qbuf + t2 * 48, W1 + l * 4608 + jj, 48, 96, (double)b1[l * 96 + jj]);
        kvbuf[i] = acc > 0 ? acc : 0;
      }
      __syncthreads();
#pragma unroll 1
      for (int i = tid; i < 1536; i += 256) {
        const int t2 = i / 48, j = i % 48;
        abuf[i] = dotW(kvbuf + t2 * 96, W2 + l * 4608 + j, 96, 48, (double)b2[l * 48 + j]);
      }
      __syncthreads();
#pragma unroll 1
      for (int i = tid; i < 1536; i += 256) xcur[i] = abuf[i];
      __syncthreads();
    }
  }
}

// ---------------------------------------------------------------------------
// ar sampling step (noinline — code dedupe). All 256 threads call uniformly.
// ---------------------------------------------------------------------------
__device__ __attribute__((noinline)) void sample_step(
    double* xtk, double* probs, double* red,
    const float* __restrict__ emb, const float* __restrict__ u,
    float* __restrict__ out_tok, int b, int step, int tid) {
  const double lg1 = dotW(xtk, emb + tid, 48, 512, 0.0);
  const double lg2 = dotW(xtk, emb + 256 + tid, 48, 512, 0.0);
  double mx = lg1 > lg2 ? lg1 : lg2;
#pragma unroll
  for (int off = 1; off < 64; off <<= 1) { const double o2 = __shfl_xor(mx, off); mx = o2 > mx ? o2 : mx; }
  if ((tid & 63) == 0) red[tid >> 6] = mx;
  __syncthreads();
  {
    const double m0 = red[0] > red[1] ? red[0] : red[1];
    const double m1 = red[2] > red[3] ? red[2] : red[3];
    mx = m0 > m1 ? m0 : m1;
  }
  probs[tid] = exp_ni(lg1 - mx);
  probs[tid + 256] = exp_ni(lg2 - mx);
  __syncthreads();
  if (tid < 64) {
    const int lane = tid;
    double loc[8], run = 0;
#pragma unroll
    for (int n2 = 0; n2 < 8; ++n2) { run += probs[lane * 8 + n2]; loc[n2] = run; }
    double incl = run;
#pragma unroll
    for (int off = 1; off < 64; off <<= 1) {
      const double t2 = __shfl_up(incl, off);
      if (lane >= off) incl += t2;
    }
    const double excl = incl - run;
    const double Ssum = __shfl(incl, 63);
    const double uu = (double)u[step * 512 + b];
    int cnt = 0;
#pragma unroll
    for (int n2 = 0; n2 < 8; ++n2) cnt += ((excl + loc[n2]) / Ssum < uu) ? 1 : 0;
#pragma unroll
    for (int off = 1; off < 64; off <<= 1) cnt += __shfl_xor(cnt, off);
    const int idx = cnt > 511 ? 511 : cnt;
    if (lane < 48) {
      const double sel = (double)emb[lane * 512 + idx];
      const double att = xtk[lane];
      out_tok[(size_t)b * 1536 + step * 48 + lane] = (float)((sel + att) - att);  // straight-through fwd
    }
  }
  __syncthreads();
}

// ---------------------------------------------------------------------------
// K6: autoregressive loop — one block of 256 threads per batch element.
// All 32 steps x 4 layers in-kernel, fp64. COMPACT body (I$-resident).
// ---------------------------------------------------------------------------
__global__ __launch_bounds__(256) void ar_kernel(
    const float* __restrict__ pos_enc, const float* __restrict__ u,
    const float* __restrict__ lnq_g, const float* __restrict__ lnq_b,
    const float* __restrict__ Wq, const float* __restrict__ bq,
    const float* __restrict__ lnk_g, const float* __restrict__ lnk_b,
    const float* __restrict__ Wk, const float* __restrict__ bk,
    const float* __restrict__ lnv_g, const float* __restrict__ lnv_b,
    const float* __restrict__ Wv, const float* __restrict__ bvv,
    const float* __restrict__ Wo, const float* __restrict__ bo,
    const float* __restrict__ mln_g, const float* __restrict__ mln_b,
    const float* __restrict__ W1, const float* __restrict__ b1,
    const float* __restrict__ W2, const float* __restrict__ b2,
    const float* __restrict__ emb,
    double* __restrict__ kcache, double* __restrict__ vcache,
    float* __restrict__ out_tok) {
  const int b = blockIdx.x, tid = threadIdx.x;
  __shared__ double xtk[48], anorm[144], qs[48], os[48], hh[96], probs[512], red[4];

#pragma unroll 1
  for (int step = 0; step < 32; ++step) {
    const int p = 32 + step;
    if (tid < 48) xtk[tid] = (double)pos_enc[step * 48 + tid];
    __syncthreads();

#pragma unroll 1
    for (int l = 0; l < 4; ++l) {
      // ---- LN1 (redundant stats) + 3 norms ----
      {
        const double2 st = ln_stats48(xtk);
        if (tid < 144) {
          const int which = tid / 48, d = tid - which * 48;
          const float* gp = which == 0 ? lnq_g : which == 1 ? lnk_g : lnv_g;
          const float* bp = which == 0 ? lnq_b : which == 1 ? lnk_b : lnv_b;
          anorm[tid] = (xtk[d] - st.x) * st.y * (double)gp[l * 48 + d] + (double)bp[l * 48 + d];
        }
      }
      __syncthreads();
      // ---- q,k,v projections ----
      if (tid < 144) {
        const int which = tid / 48, j = tid - which * 48;
        const float* Wb = which == 0 ? Wq : which == 1 ? Wk : Wv;
        const float* bbp = which == 0 ? bq : which == 1 ? bk : bvv;
        const double acc = dotW(anorm + which * 48, Wb + l * 2304 + j, 48, 48,
                                (double)bbp[l * 48 + j]);
        if (which == 0) {
          qs[j] = acc;
        } else {
          const int h = j / 6, d = j - h * 6;
          const size_t ci = ((((size_t)b * 4 + l) * 8 + h) * 64 + p) * 6 + d;
          if (which == 1) kcache[ci] = acc; else vcache[ci] = acc;
        }
      }
      __syncthreads();
      // ---- attention over [0,p): 32 lanes per head ----
      {
        const int h = tid >> 5, r = tid & 31;
        const double* kcb = kcache + ((((size_t)b * 4 + l) * 8 + h) * 64) * 6;
        const double* vcb = vcache + ((((size_t)b * 4 + l) * 8 + h) * 64) * 6;
        const double qv0 = qs[h * 6 + 0], qv1 = qs[h * 6 + 1], qv2 = qs[h * 6 + 2],
                     qv3 = qs[h * 6 + 3], qv4 = qs[h * 6 + 4], qv5 = qs[h * 6 + 5];
        const bool has2 = (r + 32) < p;
        const double* kp1 = kcb + r * 6;
        double sv1 = qv0 * kp1[0];
        sv1 = fma(qv1, kp1[1], sv1); sv1 = fma(qv2, kp1[2], sv1); sv1 = fma(qv3, kp1[3], sv1);
        sv1 = fma(qv4, kp1[4], sv1); sv1 = fma(qv5, kp1[5], sv1);
        sv1 /= SCALE_;
        double sv2 = -1e300;
        if (has2) {
          const double* kp2 = kcb + (r + 32) * 6;
          double t2 = qv0 * kp2[0];
          t2 = fma(qv1, kp2[1], t2); t2 = fma(qv2, kp2[2], t2); t2 = fma(qv3, kp2[3], t2);
          t2 = fma(qv4, kp2[4], t2); t2 = fma(qv5, kp2[5], t2);
          sv2 = t2 / SCALE_;
        }
        double mx = sv1 > sv2 ? sv1 : sv2;
#pragma unroll
        for (int off = 1; off < 32; off <<= 1) { const double o2 = __shfl_xor(mx, off); mx = o2 > mx ? o2 : mx; }
        const double e1 = exp_ni(sv1 - mx);
        const double e2 = has2 ? exp_ni(sv2 - mx) : 0.0;
        double den = e1 + e2;
        const double* vp1 = vcb + r * 6;
        double o[6];
#pragma unroll
        for (int d = 0; d < 6; ++d) o[d] = e1 * vp1[d];
        if (has2) {
          const double* vp2 = vcb + (r + 32) * 6;
#pragma unroll
          for (int d = 0; d < 6; ++d) o[d] = fma(e2, vp2[d], o[d]);
        }
#pragma unroll
        for (int off = 1; off < 32; off <<= 1) {
          den += __shfl_xor(den, off);
#pragma unroll
          for (int d = 0; d < 6; ++d) o[d] += __shfl_xor(o[d], off);
        }
        if (r == 0) {
#pragma unroll
          for (int d = 0; d < 6; ++d) os[h * 6 + d] = o[d] / den;
        }
      }
      __syncthreads();
      // ---- Wo + residual ----
      if (tid < 48)
        xtk[tid] += dotW(os, Wo + l * 2304 + tid, 48, 48, (double)bo[l * 48 + tid]);
      __syncthreads();
      // ---- MLP LN ----
      {
        const double2 st = ln_stats48(xtk);
        if (tid < 48)
          anorm[tid] = (xtk[tid] - st.x) * st.y * (double)mln_g[l * 48 + tid] + (double)mln_b[l * 48 + tid];
      }
      __syncthreads();
      // ---- MLP1 ----
      if (tid < 96) {
        const double v = dotW(anorm, W1 + l * 4608 + tid, 48, 96, (double)b1[l * 96 + tid]);
        hh[tid] = v > 0 ? v : 0;
      }
      __syncthreads();
      // ---- MLP2 (no residual) ----
      if (tid < 48)
        xtk[tid] = dotW(hh, W2 + l * 4608 + tid, 96, 48, (double)b2[l * 48 + tid]);
      __syncthreads();
    }

    sample_step(xtk, probs, red, emb, u, out_tok, b, step, tid);
  }
}

// ---------------------------------------------------------------------------
// Launch
// ---------------------------------------------------------------------------
extern "C" void kernel_launch(void* const* d_in, const int* in_sizes, int n_in,
                              void* d_out, int out_size, void* d_ws, size_t ws_size,
                              hipStream_t stream) {
  const float* x      = (const float*)d_in[0];
  const float* u      = (const float*)d_in[1];
  const float* bn_g   = (const float*)d_in[2];
  const float* bn_b   = (const float*)d_in[3];
  const float* conv_w = (const float*)d_in[4];
  const float* conv_b = (const float*)d_in[5];
  const float* tk_W1  = (const float*)d_in[6];
  const float* tk_b1  = (const float*)d_in[7];
  const float* tk_W2  = (const float*)d_in[8];
  const float* tk_b2  = (const float*)d_in[9];
  const float* lnq_g  = (const float*)d_in[10];
  const float* lnq_b  = (const float*)d_in[11];
  const float* Wq     = (const float*)d_in[12];
  const float* bq     = (const float*)d_in[13];
  const float* lnk_g  = (const float*)d_in[14];
  const float* lnk_b  = (const float*)d_in[15];
  const float* Wk     = (const float*)d_in[16];
  const float* bk     = (const float*)d_in[17];
  const float* lnv_g  = (const float*)d_in[18];
  const float* lnv_b  = (const float*)d_in[19];
  const float* Wv     = (const float*)d_in[20];
  const float* bvv    = (const float*)d_in[21];
  const float* Wo     = (const float*)d_in[22];
  const float* bo     = (const float*)d_in[23];
  const float* mln_g  = (const float*)d_in[24];
  const float* mln_b  = (const float*)d_in[25];
  const float* W1     = (const float*)d_in[26];
  const float* b1     = (const float*)d_in[27];
  const float* W2     = (const float*)d_in[28];
  const float* b2     = (const float*)d_in[29];
  const float* emb    = (const float*)d_in[30];
  const float* pos    = (const float*)d_in[31];
  const float* dW1    = (const float*)d_in[32];
  const float* db1    = (const float*)d_in[33];
  const float* dW2    = (const float*)d_in[34];
  const float* db2    = (const float*)d_in[35];
  float* out = (float*)d_out;

  char* w = (char*)d_ws;
  size_t off = 0;
  auto alloc = [&](size_t bytes) {
    size_t o = off;
    off = (off + bytes + 255) & ~(size_t)255;
    return o;
  };
  const size_t o_bnp  = alloc(512 * 14 * 8);
  const size_t o_bns  = alloc(14 * 8);
  const size_t o_xf   = alloc(16777216);   // xf fp64; later reused for split-K partials (12.6MB)
  const size_t o_h    = alloc(33554432);   // h fp64; later reused for out_tok(3.1MB)+dh(6.3MB)
  const size_t o_toks = alloc(6291456);
  const size_t o_kc   = alloc(50331648);
  const size_t o_vc   = alloc(50331648);

  double* bnp  = (double*)(w + o_bnp);
  double* bns  = (double*)(w + o_bns);
  double* xf   = (double*)(w + o_xf);
  double* hbuf = (double*)(w + o_h);
  double* toks = (double*)(w + o_toks);
  double* kc   = (double*)(w + o_kc);
  double* vc   = (double*)(w + o_vc);
  double* part = (double*)(w + o_xf);                 // reuse (xf dead after G1)
  float*  otok = (float*)(w + o_h);                   // reuse (h dead after G2)
  float*  dh   = (float*)(w + o_h + 4194304);

  // 1-2: BatchNorm stats (deterministic fp64)
  bn_partial_kernel<<<512, 256, 0, stream>>>(x, bnp);
  bn_final_kernel<<<1, 64, 0, stream>>>(bnp, bn_g, bn_b, bns);
  // 3: BN-apply + conv + flatten -> xf [512,4096]
  conv_kernel<<<8192, 256, 0, stream>>>(x, conv_w, conv_b, bns, xf);
  // 4: h = relu(xf @ tk_W1 + b1)  [512,8192]
  gemm_kernel<double, true, true><<<dim3(128, 8, 1), 256, 0, stream>>>(
      xf, tk_W1, tk_b1, hbuf, 512, 8192, 4096, 4096);
  // 5: toks = h @ tk_W2 + b2 (split-K=2 into partials, then reduce)
  gemm_kernel<double, false, false><<<dim3(24, 8, 2), 256, 0, stream>>>(
      hbuf, tk_W2, nullptr, part, 512, 1536, 8192, 4096);
  reduce2_bias_kernel<<<3072, 256, 0, stream>>>(part, tk_b2, toks, 512 * 1536, 1536);
  // 6: prefill (fills KV caches, positions 0..31)
  prefill_kernel<<<512, 256, 0, stream>>>(toks,
      lnq_g, lnq_b, Wq, bq, lnk_g, lnk_b, Wk, bk, lnv_g, lnv_b, Wv, bvv,
      Wo, bo, mln_g, mln_b, W1, b1, W2, b2, kc, vc);
  // 7: autoregressive loop (32 steps x 4 layers, 256 threads per batch elem)
  ar_kernel<<<512, 256, 0, stream>>>(pos, u,
      lnq_g, lnq_b, Wq, bq, lnk_g, lnk_b, Wk, bk, lnv_g, lnv_b, Wv, bvv,
      Wo, bo, mln_g, mln_b, W1, b1, W2, b2, emb, kc, vc, otok);
  // 8: decoder (fp32 — post-sampling, continuous path)
  gemm_kernel<float, true, true><<<dim3(48, 8, 1), 256, 0, stream>>>(
      otok, dW1, db1, dh, 512, 3072, 1536, 1536);
  gemm_kernel<float, true, false><<<dim3(28, 8, 1), 256, 0, stream>>>(
      dh, dW2, db2, out, 512, 1792, 3072, 3072);
}

// Round 4
// 4954.506 us; speedup vs baseline: 3.4185x; 1.4539x over previous
//
#include <hip/hip_runtime.h>

// ---------------------------------------------------------------------------
// Dims
// ---------------------------------------------------------------------------
// B=512 A=256 CIN=7 CC=16 D=48 H=8 DH=6 E=512 S=32 T=32 NL=4 STOT=64
// CONV_IN=4096 HID=8192 ENC=1536 DEC_HID=3072 DEC_OUT=1792
static const double SCALE_ = 6.928203230275509;  // sqrt(48)

__device__ inline float  fma_t(float a, float b, float c)  { return fmaf(a, b, c); }
__device__ inline double fma_t(double a, double b, double c){ return fma(a, b, c); }

// ---------------------------------------------------------------------------
// Helpers
// ---------------------------------------------------------------------------
// noinline dual-acc dot (prefill; pairing matches R3 exactly)
__device__ __attribute__((noinline)) double dotW(const double* a,
                                                 const float* W, int n, int ldw,
                                                 double init) {
  double a0 = init, a1 = 0.0;
#pragma unroll 2
  for (int i = 0; i < n; i += 2) {
    a0 = fma(a[i],     (double)W[i * ldw],       a0);
    a1 = fma(a[i + 1], (double)W[(i + 1) * ldw], a1);
  }
  return a0 + a1;
}

// inline quad-acc dot for ar_kernel (N known at compile time; W may be LDS)
template <int N, typename WP>
__device__ __forceinline__ double dotN(const double* a, WP W, int ldw, double init) {
  double c0 = init, c1 = 0.0, c2 = 0.0, c3 = 0.0;
#pragma unroll
  for (int i = 0; i < N; i += 4) {
    c0 = fma(a[i],     (double)W[i * ldw],       c0);
    c1 = fma(a[i + 1], (double)W[(i + 1) * ldw], c1);
    c2 = fma(a[i + 2], (double)W[(i + 2) * ldw], c2);
    c3 = fma(a[i + 3], (double)W[(i + 3) * ldw], c3);
  }
  return (c0 + c1) + (c2 + c3);
}

// LayerNorm stats over 48 elements (redundant per-thread)
__device__ __attribute__((noinline)) double2 ln_stats48(const double* x) {
  double s0 = 0, s1 = 0, q0 = 0, q1 = 0;
#pragma unroll 2
  for (int i = 0; i < 48; i += 2) {
    const double va = x[i], vb = x[i + 1];
    s0 += va; q0 = fma(va, va, q0);
    s1 += vb; q1 = fma(vb, vb, q1);
  }
  const double m = (s0 + s1) / 48.0;
  const double rs = 1.0 / sqrt((q0 + q1) / 48.0 - m * m + 1e-5);
  return make_double2(m, rs);
}

__device__ __attribute__((noinline)) double exp_ni(double x) { return exp(x); }

// ---------------------------------------------------------------------------
// K1: BatchNorm partial sums (deterministic, fp64)
// ---------------------------------------------------------------------------
__global__ __launch_bounds__(256) void bn_partial_kernel(const float* __restrict__ x,
                                                         double* __restrict__ part) {
  __shared__ double sh[256 * 14];
  const int tid = threadIdx.x;
  const int idx = blockIdx.x * 256 + tid;  // (b,a) pair, 0..131071
  const float* p = x + (size_t)idx * 7;
  for (int c = 0; c < 7; ++c) {
    double v = (double)p[c];
    sh[tid * 14 + c] = v;
    sh[tid * 14 + 7 + c] = v * v;
  }
  __syncthreads();
  if (tid < 14) {
    double acc = 0.0;
    for (int t = 0; t < 256; ++t) acc += sh[t * 14 + tid];
    part[blockIdx.x * 14 + tid] = acc;
  }
}

// K2: finalize BN stats -> per-channel scale/shift (fp64)
__global__ void bn_final_kernel(const double* __restrict__ part,
                                const float* __restrict__ g, const float* __restrict__ bb,
                                double* __restrict__ stat) {
  const int c = threadIdx.x;
  if (c < 7) {
    double s = 0.0, s2 = 0.0;
    for (int i = 0; i < 512; ++i) { s += part[i * 14 + c]; s2 += part[i * 14 + 7 + c]; }
    const double mean = s / 131072.0;
    const double var = s2 / 131072.0 - mean * mean;
    const double rstd = 1.0 / sqrt(var + 1e-5);
    const double scale = rstd * (double)g[c];
    stat[c] = scale;                          // x*scale + shift
    stat[7 + c] = (double)bb[c] - mean * scale;
  }
}

// ---------------------------------------------------------------------------
// K3: BN-apply + Conv1d(7->16,k=5,pad=2) + flatten -> xf [512, 16*256] fp64
// ---------------------------------------------------------------------------
__global__ __launch_bounds__(256) void conv_kernel(const float* __restrict__ x,
                                                   const float* __restrict__ wconv,
                                                   const float* __restrict__ cb,
                                                   const double* __restrict__ stat,
                                                   double* __restrict__ xf) {
  __shared__ double wsh[560 + 14];
  const int tid = threadIdx.x;
  for (int i = tid; i < 560; i += 256) wsh[i] = (double)wconv[i];
  for (int i = tid; i < 14; i += 256) wsh[560 + i] = stat[i];
  __syncthreads();
  const int idx = blockIdx.x * 256 + tid;    // b*4096 + o*256 + a
  const int a = idx & 255;
  const int o = (idx >> 8) & 15;
  const int b = idx >> 12;
  double acc = (double)cb[o];
  const float* xb = x + (size_t)b * (256 * 7);
  for (int k = 0; k < 5; ++k) {
    const int pos = a + k - 2;
    if (pos < 0 || pos >= 256) continue;
    const float* xp = xb + pos * 7;
    for (int ci = 0; ci < 7; ++ci) {
      const double xn = (double)xp[ci] * wsh[560 + ci] + wsh[567 + ci];
      acc = fma(xn, wsh[(o * 7 + ci) * 5 + k], acc);
    }
  }
  xf[idx] = acc;
}

// ---------------------------------------------------------------------------
// fp64 GEMM, 128x64 tile, BK=16, 256 threads, 8x4 microtile.
// C[M,N] = act(A[M,K] @ Bf[K,N] (+bias)); accumulation order over k identical
// to the old 4x4 kernel (ascending k, single accumulator) -> bit-identical.
// ---------------------------------------------------------------------------
template <typename T, bool BIAS, bool RELU>
__global__ __launch_bounds__(256) void gemm128_kernel(const T* __restrict__ A,
                                                      const float* __restrict__ Bm,
                                                      const float* __restrict__ bias,
                                                      T* __restrict__ C,
                                                      const int M, const int N, const int K,
                                                      const int kc) {
  __shared__ T As[16][130];  // [k][m], pad +2
  __shared__ T Bs[16][66];   // [k][n], pad +2
  const int tid = threadIdx.x;
  const int tx = tid & 15, ty = tid >> 4;
  const int n0 = blockIdx.x * 64, m0 = blockIdx.y * 128;
  const int k0 = blockIdx.z * kc, kend = k0 + kc;
  const int ar = tid >> 1, ac = (tid & 1) * 8;   // A: 128 rows x 16 k
  const int br = tid >> 4, bc = (tid & 15) * 4;  // B: 16 k x 64 n
  const T* Ap = A + (size_t)(m0 + ar) * K;
  const float* Bp = Bm + (size_t)br * N + n0 + bc;
  T acc[8][4] = {};
  for (int k = k0; k < kend; k += 16) {
    T av8[8];
#pragma unroll
    for (int i = 0; i < 8; ++i) av8[i] = Ap[k + ac + i];
    const float4 bw = *(const float4*)(Bp + (size_t)k * N);
#pragma unroll
    for (int i = 0; i < 8; ++i) As[ac + i][ar] = av8[i];
    Bs[br][bc] = (T)bw.x; Bs[br][bc + 1] = (T)bw.y;
    Bs[br][bc + 2] = (T)bw.z; Bs[br][bc + 3] = (T)bw.w;
    __syncthreads();
#pragma unroll
    for (int kk = 0; kk < 16; ++kk) {
      T a[8], b[4];
#pragma unroll
      for (int i = 0; i < 8; ++i) a[i] = As[kk][ty * 8 + i];
#pragma unroll
      for (int j = 0; j < 4; ++j) b[j] = Bs[kk][tx * 4 + j];
#pragma unroll
      for (int i = 0; i < 8; ++i)
#pragma unroll
        for (int j = 0; j < 4; ++j) acc[i][j] = fma_t(a[i], b[j], acc[i][j]);
    }
    __syncthreads();
  }
  T* Cp = C + (size_t)blockIdx.z * M * N;
#pragma unroll
  for (int i = 0; i < 8; ++i) {
    const int row = m0 + ty * 8 + i;
#pragma unroll
    for (int j = 0; j < 4; ++j) {
      const int col = n0 + tx * 4 + j;
      T v = acc[i][j];
      if (BIAS) v += (T)bias[col];
      if (RELU) v = v > (T)0 ? v : (T)0;
      Cp[(size_t)row * N + col] = v;
    }
  }
}

// Old 64x64 fp32 GEMM (decoder)
template <typename T, bool BIAS, bool RELU>
__global__ __launch_bounds__(256) void gemm_kernel(const T* __restrict__ A,
                                                   const float* __restrict__ Bm,
                                                   const float* __restrict__ bias,
                                                   T* __restrict__ C,
                                                   const int M, const int N, const int K,
                                                   const int kc) {
  __shared__ T As[16][65];
  __shared__ T Bs[16][65];
  const int tid = threadIdx.x;
  const int tx = tid & 15, ty = tid >> 4;
  const int n0 = blockIdx.x * 64, m0 = blockIdx.y * 64;
  const int k0 = blockIdx.z * kc, kend = k0 + kc;
  const int ar = tid >> 2, ac = (tid & 3) * 4;
  const int br = tid >> 4, bc = (tid & 15) * 4;
  const T* Ap = A + (size_t)(m0 + ar) * K;
  const float* Bp = Bm + (size_t)br * N + n0 + bc;
  T acc[4][4] = {};
  for (int k = k0; k < kend; k += 16) {
    const T a0 = Ap[k + ac], a1 = Ap[k + ac + 1], a2 = Ap[k + ac + 2], a3 = Ap[k + ac + 3];
    const float4 bw = *(const float4*)(Bp + (size_t)k * N);
    As[ac][ar] = a0; As[ac + 1][ar] = a1; As[ac + 2][ar] = a2; As[ac + 3][ar] = a3;
    Bs[br][bc] = (T)bw.x; Bs[br][bc + 1] = (T)bw.y; Bs[br][bc + 2] = (T)bw.z; Bs[br][bc + 3] = (T)bw.w;
    __syncthreads();
#pragma unroll
    for (int kk = 0; kk < 16; ++kk) {
      T av[4], bv2[4];
#pragma unroll
      for (int i = 0; i < 4; ++i) av[i] = As[kk][ty * 4 + i];
#pragma unroll
      for (int j = 0; j < 4; ++j) bv2[j] = Bs[kk][tx * 4 + j];
#pragma unroll
      for (int i = 0; i < 4; ++i)
#pragma unroll
        for (int j = 0; j < 4; ++j) acc[i][j] = fma_t(av[i], bv2[j], acc[i][j]);
    }
    __syncthreads();
  }
  T* Cp = C + (size_t)blockIdx.z * M * N;
#pragma unroll
  for (int i = 0; i < 4; ++i) {
    const int row = m0 + ty * 4 + i;
#pragma unroll
    for (int j = 0; j < 4; ++j) {
      const int col = n0 + tx * 4 + j;
      T v = acc[i][j];
      if (BIAS) v += (T)bias[col];
      if (RELU) v = v > (T)0 ? v : (T)0;
      Cp[(size_t)row * N + col] = v;
    }
  }
}

// split-K=2 reduction + bias (fp64, deterministic)
__global__ __launch_bounds__(256) void reduce2_bias_kernel(const double* __restrict__ part,
                                                           const float* __restrict__ bias,
                                                           double* __restrict__ out,
                                                           const int MN, const int N) {
  const int i = blockIdx.x * 256 + threadIdx.x;
  if (i < MN) out[i] = part[i] + part[MN + i] + (double)bias[i % N];
}

// ---------------------------------------------------------------------------
// K5: prefill — one block per batch element (unchanged from R3; bit-identical)
// ---------------------------------------------------------------------------
__global__ __launch_bounds__(256) void prefill_kernel(
    const double* __restrict__ toks,
    const float* __restrict__ lnq_g, const float* __restrict__ lnq_b,
    const float* __restrict__ Wq, const float* __restrict__ bq,
    const float* __restrict__ lnk_g, const float* __restrict__ lnk_b,
    const float* __restrict__ Wk, const float* __restrict__ bk,
    const float* __restrict__ lnv_g, const float* __restrict__ lnv_b,
    const float* __restrict__ Wv, const float* __restrict__ bvv,
    const float* __restrict__ Wo, const float* __restrict__ bo,
    const float* __restrict__ mln_g, const float* __restrict__ mln_b,
    const float* __restrict__ W1, const float* __restrict__ b1,
    const float* __restrict__ W2, const float* __restrict__ b2,
    double* __restrict__ kcache, double* __restrict__ vcache) {
  const int b = blockIdx.x, tid = threadIdx.x;
  __shared__ double xcur[1536], abuf[1536], qbuf[1536], kvbuf[3072];
  __shared__ double mean[32], rstd[32];
  double* kb = kvbuf;
  double* vb = kvbuf + 1536;

#pragma unroll 1
  for (int i = tid; i < 1536; i += 256) xcur[i] = toks[(size_t)b * 1536 + i];
  __syncthreads();

#pragma unroll 1
  for (int l = 0; l < 4; ++l) {
    if (tid < 32) {
      double s = 0.0, s2 = 0.0;
#pragma unroll 4
      for (int i = 0; i < 48; ++i) { const double v = xcur[tid * 48 + i]; s += v; s2 += v * v; }
      const double m = s / 48.0;
      mean[tid] = m;
      rstd[tid] = 1.0 / sqrt(s2 / 48.0 - m * m + 1e-5);
    }
    __syncthreads();
    const bool last = (l == 3);

    if (!last) {  // q projection
#pragma unroll 1
      for (int i = tid; i < 1536; i += 256) {
        const int t = i / 48, d = i % 48;
        abuf[i] = (xcur[i] - mean[t]) * rstd[t] * (double)lnq_g[l * 48 + d] + (double)lnq_b[l * 48 + d];
      }
      __syncthreads();
#pragma unroll 1
      for (int i = tid; i < 1536; i += 256) {
        const int t = i / 48, j = i % 48;
        qbuf[i] = dotW(abuf + t * 48, Wq + l * 2304 + j, 48, 48, (double)bq[l * 48 + j]);
      }
      __syncthreads();
    }
    // k projection
#pragma unroll 1
    for (int i = tid; i < 1536; i += 256) {
      const int t = i / 48, d = i % 48;
      abuf[i] = (xcur[i] - mean[t]) * rstd[t] * (double)lnk_g[l * 48 + d] + (double)lnk_b[l * 48 + d];
    }
    __syncthreads();
#pragma unroll 1
    for (int i = tid; i < 1536; i += 256) {
      const int t = i / 48, j = i % 48;
      kb[i] = dotW(abuf + t * 48, Wk + l * 2304 + j, 48, 48, (double)bk[l * 48 + j]);
    }
    __syncthreads();
    // v projection
#pragma unroll 1
    for (int i = tid; i < 1536; i += 256) {
      const int t = i / 48, d = i % 48;
      abuf[i] = (xcur[i] - mean[t]) * rstd[t] * (double)lnv_g[l * 48 + d] + (double)lnv_b[l * 48 + d];
    }
    __syncthreads();
#pragma unroll 1
    for (int i = tid; i < 1536; i += 256) {
      const int t = i / 48, j = i % 48;
      vb[i] = dotW(abuf + t * 48, Wv + l * 2304 + j, 48, 48, (double)bvv[l * 48 + j]);
    }
    __syncthreads();
    // store k,v to cache at pos t
#pragma unroll 1
    for (int i = tid; i < 1536; i += 256) {
      const int t = i / 48, j = i % 48;
      const int h = j / 6, d = j % 6;
      const size_t ci = ((((size_t)b * 4 + l) * 8 + h) * 64 + t) * 6 + d;
      kcache[ci] = kb[i];
      vcache[ci] = vb[i];
    }

    if (!last) {
      // attention: thread = (token t, head h). mask only (t=0, j=31).
      const int t = tid >> 3, h = tid & 7;
      const double* qp = qbuf + t * 48 + h * 6;
      const double q0 = qp[0], q1 = qp[1], q2 = qp[2], q3 = qp[3], q4 = qp[4], q5 = qp[5];
      double mx = -1e300;
#pragma unroll 4
      for (int j = 0; j < 32; ++j) {
        const double* kp = kb + j * 48 + h * 6;
        double sv = q0 * kp[0];
        sv = fma(q1, kp[1], sv); sv = fma(q2, kp[2], sv); sv = fma(q3, kp[3], sv);
        sv = fma(q4, kp[4], sv); sv = fma(q5, kp[5], sv);
        sv /= SCALE_;
        if (t == 0 && j == 31) sv -= 999.0;
        mx = sv > mx ? sv : mx;
      }
      double den = 0, o0 = 0, o1 = 0, o2 = 0, o3 = 0, o4 = 0, o5 = 0;
#pragma unroll 4
      for (int j = 0; j < 32; ++j) {
        const double* kp = kb + j * 48 + h * 6;
        double sv = q0 * kp[0];
        sv = fma(q1, kp[1], sv); sv = fma(q2, kp[2], sv); sv = fma(q3, kp[3], sv);
        sv = fma(q4, kp[4], sv); sv = fma(q5, kp[5], sv);
        sv /= SCALE_;
        if (t == 0 && j == 31) sv -= 999.0;
        const double e = exp_ni(sv - mx);
        den += e;
        const double* vp = vb + j * 48 + h * 6;
        o0 = fma(e, vp[0], o0); o1 = fma(e, vp[1], o1); o2 = fma(e, vp[2], o2);
        o3 = fma(e, vp[3], o3); o4 = fma(e, vp[4], o4); o5 = fma(e, vp[5], o5);
      }
      abuf[t * 48 + h * 6 + 0] = o0 / den;
      abuf[t * 48 + h * 6 + 1] = o1 / den;
      abuf[t * 48 + h * 6 + 2] = o2 / den;
      abuf[t * 48 + h * 6 + 3] = o3 / den;
      abuf[t * 48 + h * 6 + 4] = o4 / den;
      abuf[t * 48 + h * 6 + 5] = o5 / den;
      __syncthreads();
      // Wo + residual
#pragma unroll 1
      for (int i = tid; i < 1536; i += 256) {
        const int t2 = i / 48, j = i % 48;
        xcur[i] += dotW(abuf + t2 * 48, Wo + l * 2304 + j, 48, 48, (double)bo[l * 48 + j]);
      }
      __syncthreads();
      // MLP LN
      if (tid < 32) {
        double s = 0.0, s2 = 0.0;
#pragma unroll 4
        for (int i = 0; i < 48; ++i) { const double v = xcur[tid * 48 + i]; s += v; s2 += v * v; }
        const double m = s / 48.0;
        mean[tid] = m;
        rstd[tid] = 1.0 / sqrt(s2 / 48.0 - m * m + 1e-5);
      }
      __syncthreads();
#pragma unroll 1
      for (int i = tid; i < 1536; i += 256) {
        const int t2 = i / 48, d = i % 48;
        qbuf[i] = (xcur[i] - mean[t2]) * rstd[t2] * (double)mln_g[l * 48 + d] + (double)mln_b[l * 48 + d];
      }
      __syncthreads();
#pragma unroll 1
      for (int i = tid; i < 3072; i += 256) {
        const int t2 = i / 96, jj = i % 96;
        const double acc = dotW(qbuf + t2 * 48, W1 + l * 4608 + jj, 48, 96, (double)b1[l * 96 + jj]);
        kvbuf[i] = acc > 0 ? acc : 0;
      }
      __syncthreads();
#pragma unroll 1
      for (int i = tid; i < 1536; i += 256) {
        const int t2 = i / 48, j = i % 48;
        abuf[i] = dotW(kvbuf + t2 * 96, W2 + l * 4608 + j, 96, 48, (double)b2[l * 48 + j]);
      }
      __syncthreads();
#pragma unroll 1
      for (int i = tid; i < 1536; i += 256) xcur[i] = abuf[i];
      __syncthreads();
    }
  }
}

// ---------------------------------------------------------------------------
// ar sampling step (noinline — code dedupe). All 256 threads call uniformly.
// ---------------------------------------------------------------------------
__device__ __attribute__((noinline)) void sample_step(
    double* xtk, double* probs, double* red,
    const float* __restrict__ emb, const float* __restrict__ u,
    float* __restrict__ out_tok, int b, int step, int tid) {
  const double lg1 = dotN<48>(xtk, emb + tid, 512, 0.0);
  const double lg2 = dotN<48>(xtk, emb + 256 + tid, 512, 0.0);
  double mx = lg1 > lg2 ? lg1 : lg2;
#pragma unroll
  for (int off = 1; off < 64; off <<= 1) { const double o2 = __shfl_xor(mx, off); mx = o2 > mx ? o2 : mx; }
  if ((tid & 63) == 0) red[tid >> 6] = mx;
  __syncthreads();
  {
    const double m0 = red[0] > red[1] ? red[0] : red[1];
    const double m1 = red[2] > red[3] ? red[2] : red[3];
    mx = m0 > m1 ? m0 : m1;
  }
  probs[tid] = exp(lg1 - mx);
  probs[tid + 256] = exp(lg2 - mx);
  __syncthreads();
  if (tid < 64) {
    const int lane = tid;
    double loc[8], run = 0;
#pragma unroll
    for (int n2 = 0; n2 < 8; ++n2) { run += probs[lane * 8 + n2]; loc[n2] = run; }
    double incl = run;
#pragma unroll
    for (int off = 1; off < 64; off <<= 1) {
      const double t2 = __shfl_up(incl, off);
      if (lane >= off) incl += t2;
    }
    const double excl = incl - run;
    const double Ssum = __shfl(incl, 63);
    const double uu = (double)u[step * 512 + b];
    int cnt = 0;
#pragma unroll
    for (int n2 = 0; n2 < 8; ++n2) cnt += ((excl + loc[n2]) / Ssum < uu) ? 1 : 0;
#pragma unroll
    for (int off = 1; off < 64; off <<= 1) cnt += __shfl_xor(cnt, off);
    const int idx = cnt > 511 ? 511 : cnt;
    if (lane < 48) {
      const double sel = (double)emb[lane * 512 + idx];
      const double att = xtk[lane];
      out_tok[(size_t)b * 1536 + step * 48 + lane] = (float)((sel + att) - att);  // straight-through fwd
    }
  }
  __syncthreads();
}

// ---------------------------------------------------------------------------
// K6: autoregressive loop — one block of 256 threads per batch element.
// Per-layer weights staged into LDS (fp32, same values -> identical products).
// ---------------------------------------------------------------------------
__global__ __launch_bounds__(256) void ar_kernel(
    const float* __restrict__ pos_enc, const float* __restrict__ u,
    const float* __restrict__ lnq_g, const float* __restrict__ lnq_b,
    const float* __restrict__ Wq, const float* __restrict__ bq,
    const float* __restrict__ lnk_g, const float* __restrict__ lnk_b,
    const float* __restrict__ Wk, const float* __restrict__ bk,
    const float* __restrict__ lnv_g, const float* __restrict__ lnv_b,
    const float* __restrict__ Wv, const float* __restrict__ bvv,
    const float* __restrict__ Wo, const float* __restrict__ bo,
    const float* __restrict__ mln_g, const float* __restrict__ mln_b,
    const float* __restrict__ W1, const float* __restrict__ b1,
    const float* __restrict__ W2, const float* __restrict__ b2,
    const float* __restrict__ emb,
    double* __restrict__ kcache, double* __restrict__ vcache,
    float* __restrict__ out_tok) {
  const int b = blockIdx.x, tid = threadIdx.x;
  __shared__ double xtk[48], anorm[144], qs[48], os[48], hh[96], probs[512], red[4];
  __shared__ float wsh[9216];  // phase A: Wq|Wk|Wv|Wo (4x2304); phase B: W1|W2 (2x4608)

#pragma unroll 1
  for (int step = 0; step < 32; ++step) {
    const int p = 32 + step;
    if (tid < 48) xtk[tid] = (double)pos_enc[step * 48 + tid];
    __syncthreads();

#pragma unroll 1
    for (int l = 0; l < 4; ++l) {
      // ---- stage Wq/Wk/Wv/Wo for this layer (float4; 9 iters/thread) ----
      {
        float4* wsh4 = (float4*)wsh;
#pragma unroll 1
        for (int i = tid; i < 2304; i += 256) {
          const int a = i / 576, off4 = i - a * 576;
          const float* src = a == 0 ? Wq : a == 1 ? Wk : a == 2 ? Wv : Wo;
          wsh4[i] = ((const float4*)(src + l * 2304))[off4];
        }
      }
      // ---- LN1 (redundant stats) + 3 norms ----
      {
        const double2 st = ln_stats48(xtk);
        if (tid < 144) {
          const int which = tid / 48, d = tid - which * 48;
          const float* gp = which == 0 ? lnq_g : which == 1 ? lnk_g : lnv_g;
          const float* bp = which == 0 ? lnq_b : which == 1 ? lnk_b : lnv_b;
          anorm[tid] = (xtk[d] - st.x) * st.y * (double)gp[l * 48 + d] + (double)bp[l * 48 + d];
        }
      }
      __syncthreads();
      // ---- q,k,v projections (weights from LDS) ----
      if (tid < 144) {
        const int which = tid / 48, j = tid - which * 48;
        const float* bbp = which == 0 ? bq : which == 1 ? bk : bvv;
        const double acc = dotN<48>(anorm + which * 48, wsh + which * 2304 + j, 48,
                                    (double)bbp[l * 48 + j]);
        if (which == 0) {
          qs[j] = acc;
        } else {
          const int h = j / 6, d = j - h * 6;
          const size_t ci = ((((size_t)b * 4 + l) * 8 + h) * 64 + p) * 6 + d;
          if (which == 1) kcache[ci] = acc; else vcache[ci] = acc;
        }
      }
      __syncthreads();
      // ---- attention over [0,p): 32 lanes per head ----
      {
        const int h = tid >> 5, r = tid & 31;
        const double* kcb = kcache + ((((size_t)b * 4 + l) * 8 + h) * 64) * 6;
        const double* vcb = vcache + ((((size_t)b * 4 + l) * 8 + h) * 64) * 6;
        const double qv0 = qs[h * 6 + 0], qv1 = qs[h * 6 + 1], qv2 = qs[h * 6 + 2],
                     qv3 = qs[h * 6 + 3], qv4 = qs[h * 6 + 4], qv5 = qs[h * 6 + 5];
        const bool has2 = (r + 32) < p;
        const double* kp1 = kcb + r * 6;
        double sv1 = qv0 * kp1[0];
        sv1 = fma(qv1, kp1[1], sv1); sv1 = fma(qv2, kp1[2], sv1); sv1 = fma(qv3, kp1[3], sv1);
        sv1 = fma(qv4, kp1[4], sv1); sv1 = fma(qv5, kp1[5], sv1);
        sv1 /= SCALE_;
        double sv2 = -1e300;
        if (has2) {
          const double* kp2 = kcb + (r + 32) * 6;
          double t2 = qv0 * kp2[0];
          t2 = fma(qv1, kp2[1], t2); t2 = fma(qv2, kp2[2], t2); t2 = fma(qv3, kp2[3], t2);
          t2 = fma(qv4, kp2[4], t2); t2 = fma(qv5, kp2[5], t2);
          sv2 = t2 / SCALE_;
        }
        double mx = sv1 > sv2 ? sv1 : sv2;
#pragma unroll
        for (int off = 1; off < 32; off <<= 1) { const double o2 = __shfl_xor(mx, off); mx = o2 > mx ? o2 : mx; }
        const double e1 = exp(sv1 - mx);
        const double e2 = has2 ? exp(sv2 - mx) : 0.0;
        double den = e1 + e2;
        const double* vp1 = vcb + r * 6;
        double o[6];
#pragma unroll
        for (int d = 0; d < 6; ++d) o[d] = e1 * vp1[d];
        if (has2) {
          const double* vp2 = vcb + (r + 32) * 6;
#pragma unroll
          for (int d = 0; d < 6; ++d) o[d] = fma(e2, vp2[d], o[d]);
        }
#pragma unroll
        for (int off = 1; off < 32; off <<= 1) {
          den += __shfl_xor(den, off);
#pragma unroll
          for (int d = 0; d < 6; ++d) o[d] += __shfl_xor(o[d], off);
        }
        if (r == 0) {
#pragma unroll
          for (int d = 0; d < 6; ++d) os[h * 6 + d] = o[d] / den;
        }
      }
      __syncthreads();
      // ---- Wo + residual (weights from LDS) ----
      if (tid < 48)
        xtk[tid] += dotN<48>(os, wsh + 3 * 2304 + tid, 48, (double)bo[l * 48 + tid]);
      __syncthreads();
      // ---- stage W1|W2 (overwrites wsh; Wo use is behind the barrier) ----
      {
        float4* wsh4 = (float4*)wsh;
#pragma unroll 1
        for (int i = tid; i < 2304; i += 256) {
          const int a = i / 1152, off4 = i - a * 1152;
          const float* src = a == 0 ? W1 : W2;
          wsh4[i] = ((const float4*)(src + l * 4608))[off4];
        }
      }
      // ---- MLP LN ----
      {
        const double2 st = ln_stats48(xtk);
        if (tid < 48)
          anorm[tid] = (xtk[tid] - st.x) * st.y * (double)mln_g[l * 48 + tid] + (double)mln_b[l * 48 + tid];
      }
      __syncthreads();
      // ---- MLP1 (weights from LDS) ----
      if (tid < 96) {
        const double v = dotN<48>(anorm, wsh + tid, 96, (double)b1[l * 96 + tid]);
        hh[tid] = v > 0 ? v : 0;
      }
      __syncthreads();
      // ---- MLP2 (no residual; weights from LDS) ----
      if (tid < 48)
        xtk[tid] = dotN<96>(hh, wsh + 4608 + tid, 48, (double)b2[l * 48 + tid]);
      __syncthreads();
    }

    sample_step(xtk, probs, red, emb, u, out_tok, b, step, tid);
  }
}

// ---------------------------------------------------------------------------
// Launch
// ---------------------------------------------------------------------------
extern "C" void kernel_launch(void* const* d_in, const int* in_sizes, int n_in,
                              void* d_out, int out_size, void* d_ws, size_t ws_size,
                              hipStream_t stream) {
  const float* x      = (const float*)d_in[0];
  const float* u      = (const float*)d_in[1];
  const float* bn_g   = (const float*)d_in[2];
  const float* bn_b   = (const float*)d_in[3];
  const float* conv_w = (const float*)d_in[4];
  const float* conv_b = (const float*)d_in[5];
  const float* tk_W1  = (const float*)d_in[6];
  const float* tk_b1  = (const float*)d_in[7];
  const float* tk_W2  = (const float*)d_in[8];
  const float* tk_b2  = (const float*)d_in[9];
  const float* lnq_g  = (const float*)d_in[10];
  const float* lnq_b  = (const float*)d_in[11];
  const float* Wq     = (const float*)d_in[12];
  const float* bq     = (const float*)d_in[13];
  const float* lnk_g  = (const float*)d_in[14];
  const float* lnk_b  = (const float*)d_in[15];
  const float* Wk     = (const float*)d_in[16];
  const float* bk     = (const float*)d_in[17];
  const float* lnv_g  = (const float*)d_in[18];
  const float* lnv_b  = (const float*)d_in[19];
  const float* Wv     = (const float*)d_in[20];
  const float* bvv    = (const float*)d_in[21];
  const float* Wo     = (const float*)d_in[22];
  const float* bo     = (const float*)d_in[23];
  const float* mln_g  = (const float*)d_in[24];
  const float* mln_b  = (const float*)d_in[25];
  const float* W1     = (const float*)d_in[26];
  const float* b1     = (const float*)d_in[27];
  const float* W2     = (const float*)d_in[28];
  const float* b2     = (const float*)d_in[29];
  const float* emb    = (const float*)d_in[30];
  const float* pos    = (const float*)d_in[31];
  const float* dW1    = (const float*)d_in[32];
  const float* db1    = (const float*)d_in[33];
  const float* dW2    = (const float*)d_in[34];
  const float* db2    = (const float*)d_in[35];
  float* out = (float*)d_out;

  char* w = (char*)d_ws;
  size_t off = 0;
  auto alloc = [&](size_t bytes) {
    size_t o = off;
    off = (off + bytes + 255) & ~(size_t)255;
    return o;
  };
  const size_t o_bnp  = alloc(512 * 14 * 8);
  const size_t o_bns  = alloc(14 * 8);
  const size_t o_xf   = alloc(16777216);   // xf fp64; later reused for split-K partials (12.6MB)
  const size_t o_h    = alloc(33554432);   // h fp64; later reused for out_tok(3.1MB)+dh(6.3MB)
  const size_t o_toks = alloc(6291456);
  const size_t o_kc   = alloc(50331648);
  const size_t o_vc   = alloc(50331648);

  double* bnp  = (double*)(w + o_bnp);
  double* bns  = (double*)(w + o_bns);
  double* xf   = (double*)(w + o_xf);
  double* hbuf = (double*)(w + o_h);
  double* toks = (double*)(w + o_toks);
  double* kc   = (double*)(w + o_kc);
  double* vc   = (double*)(w + o_vc);
  double* part = (double*)(w + o_xf);                 // reuse (xf dead after G1)
  float*  otok = (float*)(w + o_h);                   // reuse (h dead after G2)
  float*  dh   = (float*)(w + o_h + 4194304);

  // 1-2: BatchNorm stats (deterministic fp64)
  bn_partial_kernel<<<512, 256, 0, stream>>>(x, bnp);
  bn_final_kernel<<<1, 64, 0, stream>>>(bnp, bn_g, bn_b, bns);
  // 3: BN-apply + conv + flatten -> xf [512,4096]
  conv_kernel<<<8192, 256, 0, stream>>>(x, conv_w, conv_b, bns, xf);
  // 4: h = relu(xf @ tk_W1 + b1)  [512,8192]  (128x64 tile fp64)
  gemm128_kernel<double, true, true><<<dim3(128, 4, 1), 256, 0, stream>>>(
      xf, tk_W1, tk_b1, hbuf, 512, 8192, 4096, 4096);
  // 5: toks = h @ tk_W2 + b2 (split-K=2 into partials, then reduce)
  gemm128_kernel<double, false, false><<<dim3(24, 4, 2), 256, 0, stream>>>(
      hbuf, tk_W2, nullptr, part, 512, 1536, 8192, 4096);
  reduce2_bias_kernel<<<3072, 256, 0, stream>>>(part, tk_b2, toks, 512 * 1536, 1536);
  // 6: prefill (fills KV caches, positions 0..31)
  prefill_kernel<<<512, 256, 0, stream>>>(toks,
      lnq_g, lnq_b, Wq, bq, lnk_g, lnk_b, Wk, bk, lnv_g, lnv_b, Wv, bvv,
      Wo, bo, mln_g, mln_b, W1, b1, W2, b2, kc, vc);
  // 7: autoregressive loop (32 steps x 4 layers, 256 threads per batch elem)
  ar_kernel<<<512, 256, 0, stream>>>(pos, u,
      lnq_g, lnq_b, Wq, bq, lnk_g, lnk_b, Wk, bk, lnv_g, lnv_b, Wv, bvv,
      Wo, bo, mln_g, mln_b, W1, b1, W2, b2, emb, kc, vc, otok);
  // 8: decoder (fp32 — post-sampling, continuous path)
  gemm_kernel<float, true, true><<<dim3(48, 8, 1), 256, 0, stream>>>(
      otok, dW1, db1, dh, 512, 3072, 1536, 1536);
  gemm_kernel<float, true, false><<<dim3(28, 8, 1), 256, 0, stream>>>(
      dh, dW2, db2, out, 512, 1792, 3072, 3072);
}